// Round 1
// baseline (525.760 us; speedup 1.0000x reference)
//
#include <hip/hip_runtime.h>
#include <math.h>

#define DIM 128
#define BATCH 2048
#define TM 128          // tg rows per tile
#define TN 128          // prev rows per tile
#define NCHUNK 16       // j-chunks (grid.y)
#define JT_PER_CHUNK 32 // 65536 / NCHUNK / TN

// ---------- kernel 1: prev2[j] = sum_k prev[j][k]^2 ----------
__global__ __launch_bounds__(256) void k_prev2(const float* __restrict__ prev,
                                               float* __restrict__ prev2,
                                               int nprev) {
    const int wave = threadIdx.x >> 6;
    const int lane = threadIdx.x & 63;
    const int row = blockIdx.x * 4 + wave;
    if (row >= nprev) return;
    const float2 v = *reinterpret_cast<const float2*>(prev + (size_t)row * DIM + 2 * lane);
    float s = v.x * v.x + v.y * v.y;
    #pragma unroll
    for (int m = 1; m < 64; m <<= 1) s += __shfl_xor(s, m);
    if (lane == 0) prev2[row] = s;
}

// ---------- kernel 2: tiled fp32 GEMM + per-(row,chunk) argmin ----------
// grid = (BATCH/TM, NCHUNK), block = 256
// Each block: tg tile (128 rows) vs one chunk of 4096 prev rows.
// d2'(i,j) = prev2[j] - 2*dot(tg_i, prev_j)   (tg^2 term is row-constant)
__global__ __launch_bounds__(256, 1) void k_argmin(
    const float* __restrict__ tg,     // [BATCH][DIM]
    const float* __restrict__ prev,   // [nprev][DIM]
    const float* __restrict__ prev2,  // [nprev]
    float2* __restrict__ partial)     // [BATCH][NCHUNK] (val, idx-bits)
{
    // swizzled float4 tiles: element (row, kk) stored at [row*32 + (kk ^ (row&7))]
    __shared__ float4 tgL[TM * 32];   // 64 KiB
    __shared__ float4 pvL[TN * 32];   // 64 KiB
    __shared__ float  p2L[TN];

    const int t = threadIdx.x;
    const int rowTile = blockIdx.x;
    const int chunk = blockIdx.y;

    // ---- stage tg tile (coalesced float4, swizzled LDS write) ----
    const float4* tgG = reinterpret_cast<const float4*>(tg + (size_t)rowTile * TM * DIM);
    #pragma unroll
    for (int i = 0; i < 16; ++i) {
        const int idx = t + 256 * i;          // 0..4095
        const int row = idx >> 5, kk = idx & 31;
        tgL[row * 32 + (kk ^ (row & 7))] = tgG[idx];
    }

    const int tx = t & 15, ty = t >> 4;
    const int sa = ty & 7, sb = tx & 7;

    float minval[8];
    int   minidx[8];
    #pragma unroll
    for (int ri = 0; ri < 8; ++ri) { minval[ri] = INFINITY; minidx[ri] = 0x7fffffff; }

    const int jchunk0 = chunk * (JT_PER_CHUNK * TN);

    for (int jt = 0; jt < JT_PER_CHUNK; ++jt) {
        const int j0 = jchunk0 + jt * TN;
        __syncthreads();   // previous iteration's LDS reads complete (also orders tg staging)
        const float4* pvG = reinterpret_cast<const float4*>(prev + (size_t)j0 * DIM);
        #pragma unroll
        for (int i = 0; i < 16; ++i) {
            const int idx = t + 256 * i;
            const int row = idx >> 5, kk = idx & 31;
            pvL[row * 32 + (kk ^ (row & 7))] = pvG[idx];
        }
        if (t < TN) p2L[t] = prev2[j0 + t];
        __syncthreads();

        float acc[8][8];
        #pragma unroll
        for (int ri = 0; ri < 8; ++ri)
            #pragma unroll
            for (int ci = 0; ci < 8; ++ci) acc[ri][ci] = 0.f;

        #pragma unroll 2
        for (int kk = 0; kk < 32; ++kk) {
            float4 a[8], b[8];
            const int ka = kk ^ sa, kb = kk ^ sb;
            #pragma unroll
            for (int ri = 0; ri < 8; ++ri) a[ri] = tgL[(ty + 16 * ri) * 32 + ka];
            #pragma unroll
            for (int ci = 0; ci < 8; ++ci) b[ci] = pvL[(tx + 16 * ci) * 32 + kb];
            #pragma unroll
            for (int ri = 0; ri < 8; ++ri)
                #pragma unroll
                for (int ci = 0; ci < 8; ++ci) {
                    acc[ri][ci] += a[ri].x * b[ci].x;
                    acc[ri][ci] += a[ri].y * b[ci].y;
                    acc[ri][ci] += a[ri].z * b[ci].z;
                    acc[ri][ci] += a[ri].w * b[ci].w;
                }
        }

        // argmin update (ci ascending => j ascending: first-occurrence semantics)
        #pragma unroll
        for (int ci = 0; ci < 8; ++ci) {
            const int jl = tx + 16 * ci;
            const int jg = j0 + jl;
            const float pj = p2L[jl];
            #pragma unroll
            for (int ri = 0; ri < 8; ++ri) {
                const float d = pj - 2.f * acc[ri][ci];
                if (d < minval[ri]) { minval[ri] = d; minidx[ri] = jg; }
            }
        }
    }

    // ---- block reduction across tx (16 threads per row) ----
    __syncthreads();
    float2* red = reinterpret_cast<float2*>(pvL);  // 128*16 float2 = 16 KiB (reuse)
    #pragma unroll
    for (int ri = 0; ri < 8; ++ri) {
        const int row = ty + 16 * ri;
        red[row * 16 + tx] = make_float2(minval[ri], __int_as_float(minidx[ri]));
    }
    __syncthreads();
    if (t < TM) {
        float bv = INFINITY; int bi = 0x7fffffff;
        #pragma unroll
        for (int e = 0; e < 16; ++e) {
            const float2 p = red[t * 16 + e];
            const int pi = __float_as_int(p.y);
            if (p.x < bv || (p.x == bv && pi < bi)) { bv = p.x; bi = pi; }
        }
        partial[(size_t)(rowTile * TM + t) * NCHUNK + chunk] =
            make_float2(bv, __int_as_float(bi));
    }
}

// ---------- kernel 3: final reduce + exact LP values/grads ----------
// one wave per row; grid = BATCH/4, block = 256
__global__ __launch_bounds__(256) void k_final(
    const float* __restrict__ tg, const float* __restrict__ rg,
    const float* __restrict__ prev, const float2* __restrict__ partial,
    float* __restrict__ out_vals, float* __restrict__ out_grads)
{
    const int wave = threadIdx.x >> 6, lane = threadIdx.x & 63;
    const int i = blockIdx.x * 4 + wave;

    float bv = INFINITY; int bi = 0x7fffffff;
    if (lane < NCHUNK) {
        const float2 p = partial[(size_t)i * NCHUNK + lane];
        bv = p.x; bi = __float_as_int(p.y);
    }
    #pragma unroll
    for (int m = 1; m < 16; m <<= 1) {
        const float ov = __shfl_xor(bv, m);
        const int   oi = __shfl_xor(bi, m);
        if (ov < bv || (ov == bv && oi < bi)) { bv = ov; bi = oi; }
    }
    bi = __shfl(bi, 0);

    const float2 g = *reinterpret_cast<const float2*>(tg   + (size_t)i  * DIM + 2 * lane);
    const float2 s = *reinterpret_cast<const float2*>(prev + (size_t)bi * DIM + 2 * lane);
    const float2 r = *reinterpret_cast<const float2*>(rg   + (size_t)i  * DIM + 2 * lane);
    const float dsx = g.x - s.x, dsy = g.y - s.y;
    const float drx = g.x - r.x, dry = g.y - r.y;
    float ds = dsx * dsx + dsy * dsy;
    float dr = drx * drx + dry * dry;
    #pragma unroll
    for (int m = 1; m < 64; m <<= 1) { ds += __shfl_xor(ds, m); dr += __shfl_xor(dr, m); }
    const float sds = sqrtf(ds), sdr = sqrtf(dr);
    if (lane == 0) out_vals[i] = sds - sdr;
    const float is = 1.0f / sds, ir = 1.0f / sdr;
    float2 gr;
    gr.x = dsx * is - drx * ir;
    gr.y = dsy * is - dry * ir;
    *reinterpret_cast<float2*>(out_grads + (size_t)i * DIM + 2 * lane) = gr;
}

extern "C" void kernel_launch(void* const* d_in, const int* in_sizes, int n_in,
                              void* d_out, int out_size, void* d_ws, size_t ws_size,
                              hipStream_t stream) {
    const float* target  = (const float*)d_in[0];
    const float* reached = (const float*)d_in[1];
    const int n_total = in_sizes[0] / DIM;
    const int nprev = n_total - BATCH;          // 65536

    const float* tg   = target  + (size_t)nprev * DIM;
    const float* rg   = reached + (size_t)nprev * DIM;
    const float* prev = reached;

    float*  prev2   = (float*)d_ws;                                       // 256 KiB
    float2* partial = (float2*)((char*)d_ws + (size_t)nprev * sizeof(float)); // 256 KiB

    float* out_vals  = (float*)d_out;
    float* out_grads = out_vals + BATCH;

    k_prev2<<<nprev / 4, 256, 0, stream>>>(prev, prev2, nprev);

    dim3 grid(BATCH / TM, NCHUNK);
    k_argmin<<<grid, 256, 0, stream>>>(tg, prev, prev2, partial);

    k_final<<<BATCH / 4, 256, 0, stream>>>(tg, rg, prev, partial, out_vals, out_grads);
}

// Round 2
// 263.162 us; speedup vs baseline: 1.9979x; 1.9979x over previous
//
#include <hip/hip_runtime.h>
#include <math.h>

#define DIM 128
#define BATCH 2048
#define NPREV 65536
#define NS 12      // virtual k-steps of 32 (hi*hi x4, hi*lo x4, lo*hi x4)
#define NJT 4      // n-tiles (128 cols) per block
#define NCHUNKS 128
#define DELTA 0.05f

typedef __attribute__((ext_vector_type(8))) short bf16x8;
typedef __attribute__((ext_vector_type(4))) float f32x4;

static __device__ __forceinline__ unsigned short f2bf(float f) {
    unsigned int u = __float_as_uint(f);
    u += 0x7FFF + ((u >> 16) & 1);          // round-to-nearest-even
    return (unsigned short)(u >> 16);
}
static __device__ __forceinline__ float bf2f(unsigned short h) {
    return __uint_as_float(((unsigned int)h) << 16);
}

#define GLOAD16(g, l) __builtin_amdgcn_global_load_lds( \
    (const __attribute__((address_space(1))) void*)(g), \
    (__attribute__((address_space(3))) void*)(l), 16, 0, 0)

// ---------- prev2[j] = ||prev_j||^2 ----------
__global__ __launch_bounds__(256) void k_prev2(const float* __restrict__ prev,
                                               float* __restrict__ prev2,
                                               int nprev) {
    const int wave = threadIdx.x >> 6;
    const int lane = threadIdx.x & 63;
    const int row = blockIdx.x * 4 + wave;
    if (row >= nprev) return;
    const float2 v = *reinterpret_cast<const float2*>(prev + (size_t)row * DIM + 2 * lane);
    float s = v.x * v.x + v.y * v.y;
    #pragma unroll
    for (int m = 1; m < 64; m <<= 1) s += __shfl_xor(s, m);
    if (lane == 0) prev2[row] = s;
}

// ---------- split-bf16 conversion into pre-tiled, pre-swizzled layout ----------
// dst tile (rtile, kstep): 8 KB = 512 x 16B chunks; chunk a16 holds
// row rloc = a16>>2, k-slot ks = (a16&3) ^ ((rloc>>1)&3)  (the LDS swizzle image)
// kstep 0..3 => hi part, k0 = kstep*32 ; kstep 4..7 => lo part, k0 = (kstep-4)*32
__global__ __launch_bounds__(256) void k_conv(const float* __restrict__ src,
                                              unsigned short* __restrict__ dst,
                                              int nchunks) {
    int id = blockIdx.x * 256 + threadIdx.x;
    if (id >= nchunks) return;
    int tile = id >> 9;
    int a16  = id & 511;
    int rloc = a16 >> 2;
    int slot = a16 & 3;
    int ks   = slot ^ ((rloc >> 1) & 3);
    int kstep = tile & 7;
    int rtile = tile >> 3;
    int k0 = (kstep & 3) * 32 + ks * 8;
    const float* s = src + (size_t)(rtile * 128 + rloc) * DIM + k0;
    float4 f0 = *reinterpret_cast<const float4*>(s);
    float4 f1 = *reinterpret_cast<const float4*>(s + 4);
    float f[8] = {f0.x, f0.y, f0.z, f0.w, f1.x, f1.y, f1.z, f1.w};
    union { unsigned short us[8]; uint4 v; } o;
    if (kstep < 4) {
        #pragma unroll
        for (int e = 0; e < 8; ++e) o.us[e] = f2bf(f[e]);
    } else {
        #pragma unroll
        for (int e = 0; e < 8; ++e) {
            unsigned short h = f2bf(f[e]);
            o.us[e] = f2bf(f[e] - bf2f(h));
        }
    }
    *reinterpret_cast<uint4*>(dst + (size_t)id * 8) = o.v;
}

// ---------- MFMA GEMM (128x128 tile, K=384 virtual) + fused argmin ----------
// grid = (16 mtiles, 128 chunks); each block loops NJT=4 n-tiles of 128 cols.
__global__ __launch_bounds__(256, 2) void k_gemm_argmin(
    const unsigned short* __restrict__ Ab,   // [16*8 tiles][4096]
    const unsigned short* __restrict__ Bb,   // [512*8 tiles][4096]
    const float* __restrict__ prev2,
    float2* __restrict__ partial)            // [BATCH][NCHUNKS]
{
    __shared__ __align__(16) unsigned short At[2][4096];
    __shared__ __align__(16) unsigned short Bt[2][4096];
    __shared__ float2 red[128][2];
    __shared__ float2 runTop[128];
    __shared__ float  p2L[128];

    const int t = threadIdx.x;
    const int lane = t & 63;
    const int w  = t >> 6;
    const int wm = w >> 1, wn = w & 1;
    const int mtile = blockIdx.x;
    const int chunk = blockIdx.y;

    if (t < 128) runTop[t] = make_float2(INFINITY, __int_as_float(0x7fffffff));

    // fragment byte offsets (hoisted): row-major [128][32] bf16 tile, swizzled slots
    int a_off[4], b_off[4];
    #pragma unroll
    for (int fm = 0; fm < 4; ++fm) {
        int row = wm * 64 + fm * 16 + (lane & 15);
        a_off[fm] = row * 64 + (((lane >> 4) ^ ((row >> 1) & 3)) << 4);
    }
    #pragma unroll
    for (int fn = 0; fn < 4; ++fn) {
        int col = wn * 64 + fn * 16 + (lane & 15);
        b_off[fn] = col * 64 + (((lane >> 4) ^ ((col >> 1) & 3)) << 4);
    }

    for (int jt = 0; jt < NJT; ++jt) {
        const int ntile = chunk * NJT + jt;
        if (t < 128) p2L[t] = prev2[ntile * 128 + t];

        // prologue stage s=0 into buf0
        {
            const unsigned short* ga = Ab + ((size_t)(mtile * 8 + 0) << 12);
            const unsigned short* gb = Bb + ((size_t)(ntile * 8 + 0) << 12);
            GLOAD16(ga + t * 8,        &At[0][t * 8]);
            GLOAD16(ga + 2048 + t * 8, &At[0][2048 + t * 8]);
            GLOAD16(gb + t * 8,        &Bt[0][t * 8]);
            GLOAD16(gb + 2048 + t * 8, &Bt[0][2048 + t * 8]);
        }
        __syncthreads();

        f32x4 acc[4][4];
        #pragma unroll
        for (int fm = 0; fm < 4; ++fm)
            #pragma unroll
            for (int fn = 0; fn < 4; ++fn)
                acc[fm][fn] = (f32x4){0.f, 0.f, 0.f, 0.f};

        #pragma unroll
        for (int s = 0; s < NS; ++s) {
            if (s + 1 < NS) {   // stage next k-step into other buffer
                const int sn = s + 1;
                const int a_ks = (sn < 8) ? (sn & 3) : (sn - 4);
                const int b_ks = (sn < 8) ? sn : (sn & 3);
                const int buf = sn & 1;
                const unsigned short* ga = Ab + ((size_t)(mtile * 8 + a_ks) << 12);
                const unsigned short* gb = Bb + ((size_t)(ntile * 8 + b_ks) << 12);
                GLOAD16(ga + t * 8,        &At[buf][t * 8]);
                GLOAD16(ga + 2048 + t * 8, &At[buf][2048 + t * 8]);
                GLOAD16(gb + t * 8,        &Bt[buf][t * 8]);
                GLOAD16(gb + 2048 + t * 8, &Bt[buf][2048 + t * 8]);
            }
            const int cur = s & 1;
            bf16x8 af[4], bfr[4];
            #pragma unroll
            for (int fm = 0; fm < 4; ++fm)
                af[fm] = *reinterpret_cast<const bf16x8*>(
                    reinterpret_cast<const char*>(At[cur]) + a_off[fm]);
            #pragma unroll
            for (int fn = 0; fn < 4; ++fn)
                bfr[fn] = *reinterpret_cast<const bf16x8*>(
                    reinterpret_cast<const char*>(Bt[cur]) + b_off[fn]);
            #pragma unroll
            for (int fm = 0; fm < 4; ++fm)
                #pragma unroll
                for (int fn = 0; fn < 4; ++fn)
                    acc[fm][fn] = __builtin_amdgcn_mfma_f32_16x16x32_bf16(
                        af[fm], bfr[fn], acc[fm][fn], 0, 0, 0);
            __syncthreads();
        }

        // ---- fused argmin epilogue: d = prev2[j] - 2*dot ----
        #pragma unroll
        for (int fm = 0; fm < 4; ++fm) {
            #pragma unroll
            for (int rg = 0; rg < 4; ++rg) {
                float bv = INFINITY; int bj = 0x7fffffff;
                #pragma unroll
                for (int fn = 0; fn < 4; ++fn) {
                    int jl = wn * 64 + fn * 16 + (lane & 15);
                    float d = p2L[jl] - 2.0f * acc[fm][fn][rg];
                    if (d < bv) { bv = d; bj = jl; }   // fn asc => j asc, first-occurrence
                }
                bj += ntile * 128;                     // globalize
                #pragma unroll
                for (int m = 1; m < 16; m <<= 1) {     // reduce across the 16-lane group
                    float ov = __shfl_xor(bv, m);
                    int   oj = __shfl_xor(bj, m);
                    if (ov < bv || (ov == bv && oj < bj)) { bv = ov; bj = oj; }
                }
                if ((lane & 15) == 0) {
                    int rowb = wm * 64 + fm * 16 + ((lane >> 4) << 2) + rg;
                    red[rowb][wn] = make_float2(bv, __int_as_float(bj));
                }
            }
        }
        __syncthreads();
        if (t < 128) {
            float2 a = red[t][0], b = red[t][1];
            int ja = __float_as_int(a.y), jb = __float_as_int(b.y);
            float2 m = (b.x < a.x || (b.x == a.x && jb < ja)) ? b : a;
            float2 rt = runTop[t];
            int jm = __float_as_int(m.y), jr = __float_as_int(rt.y);
            if (m.x < rt.x || (m.x == rt.x && jm < jr)) runTop[t] = m;
        }
        __syncthreads();
    }

    if (t < 128)
        partial[(size_t)(mtile * 128 + t) * NCHUNKS + chunk] = runTop[t];
}

// ---------- final: global reduce + exact fp32 recheck + LP vals/grads ----------
__global__ __launch_bounds__(256) void k_final2(
    const float* __restrict__ tg, const float* __restrict__ rg,
    const float* __restrict__ prev, const float2* __restrict__ partial,
    float* __restrict__ out_vals, float* __restrict__ out_grads)
{
    const int wv = threadIdx.x >> 6, lane = threadIdx.x & 63;
    const int i = blockIdx.x * 4 + wv;
    const float2* P = partial + (size_t)i * NCHUNKS;
    float2 e0 = P[lane], e1 = P[lane + 64];
    float v0 = e0.x; int j0 = __float_as_int(e0.y);
    float v1 = e1.x; int j1 = __float_as_int(e1.y);

    float bv; int bj;
    if (v0 < v1 || (v0 == v1 && j0 < j1)) { bv = v0; bj = j0; } else { bv = v1; bj = j1; }
    #pragma unroll
    for (int m = 1; m < 64; m <<= 1) {
        float ov = __shfl_xor(bv, m); int oj = __shfl_xor(bj, m);
        if (ov < bv || (ov == bv && oj < bj)) { bv = ov; bj = oj; }
    }

    unsigned long long m0 = __ballot(v0 <= bv + DELTA);
    unsigned long long m1 = __ballot(v1 <= bv + DELTA);
    const float2 g = *reinterpret_cast<const float2*>(tg + (size_t)i * DIM + 2 * lane);

    float bestd = INFINITY; int bestj = 0x7fffffff;
    while (m0 | m1) {          // ascending chunk => ascending j (first-occurrence safe)
        int cj;
        if (m0) { int src = __ffsll(m0) - 1; m0 &= m0 - 1; cj = __shfl(j0, src); }
        else    { int src = __ffsll(m1) - 1; m1 &= m1 - 1; cj = __shfl(j1, src); }
        const float2 p = *reinterpret_cast<const float2*>(prev + (size_t)cj * DIM + 2 * lane);
        float dx = g.x - p.x, dy = g.y - p.y;
        float d = dx * dx + dy * dy;
        #pragma unroll
        for (int m = 1; m < 64; m <<= 1) d += __shfl_xor(d, m);
        if (d < bestd) { bestd = d; bestj = cj; }
    }

    const float2 s = *reinterpret_cast<const float2*>(prev + (size_t)bestj * DIM + 2 * lane);
    const float2 r = *reinterpret_cast<const float2*>(rg + (size_t)i * DIM + 2 * lane);
    const float dsx = g.x - s.x, dsy = g.y - s.y;
    const float drx = g.x - r.x, dry = g.y - r.y;
    float ds = dsx * dsx + dsy * dsy;
    float dr = drx * drx + dry * dry;
    #pragma unroll
    for (int m = 1; m < 64; m <<= 1) { ds += __shfl_xor(ds, m); dr += __shfl_xor(dr, m); }
    const float sds = sqrtf(ds), sdr = sqrtf(dr);
    if (lane == 0) out_vals[i] = sds - sdr;
    const float is = 1.0f / sds, ir = 1.0f / sdr;
    float2 gr;
    gr.x = dsx * is - drx * ir;
    gr.y = dsy * is - dry * ir;
    *reinterpret_cast<float2*>(out_grads + (size_t)i * DIM + 2 * lane) = gr;
}

// ================= fallback (round-1 verified fp32 path) =================
#define TM 128
#define TN 128
#define FNCHUNK 16
#define JT_PER_CHUNK 32

__global__ __launch_bounds__(256, 1) void k_argmin_fb(
    const float* __restrict__ tg, const float* __restrict__ prev,
    const float* __restrict__ prev2, float2* __restrict__ partial)
{
    __shared__ float4 tgL[TM * 32];
    __shared__ float4 pvL[TN * 32];
    __shared__ float  p2L[TN];
    const int t = threadIdx.x;
    const int rowTile = blockIdx.x;
    const int chunk = blockIdx.y;
    const float4* tgG = reinterpret_cast<const float4*>(tg + (size_t)rowTile * TM * DIM);
    #pragma unroll
    for (int i = 0; i < 16; ++i) {
        const int idx = t + 256 * i;
        const int row = idx >> 5, kk = idx & 31;
        tgL[row * 32 + (kk ^ (row & 7))] = tgG[idx];
    }
    const int tx = t & 15, ty = t >> 4;
    const int sa = ty & 7, sb = tx & 7;
    float minval[8]; int minidx[8];
    #pragma unroll
    for (int ri = 0; ri < 8; ++ri) { minval[ri] = INFINITY; minidx[ri] = 0x7fffffff; }
    const int jchunk0 = chunk * (JT_PER_CHUNK * TN);
    for (int jt = 0; jt < JT_PER_CHUNK; ++jt) {
        const int j0 = jchunk0 + jt * TN;
        __syncthreads();
        const float4* pvG = reinterpret_cast<const float4*>(prev + (size_t)j0 * DIM);
        #pragma unroll
        for (int i = 0; i < 16; ++i) {
            const int idx = t + 256 * i;
            const int row = idx >> 5, kk = idx & 31;
            pvL[row * 32 + (kk ^ (row & 7))] = pvG[idx];
        }
        if (t < TN) p2L[t] = prev2[j0 + t];
        __syncthreads();
        float acc[8][8];
        #pragma unroll
        for (int ri = 0; ri < 8; ++ri)
            #pragma unroll
            for (int ci = 0; ci < 8; ++ci) acc[ri][ci] = 0.f;
        #pragma unroll 2
        for (int kk = 0; kk < 32; ++kk) {
            float4 a[8], b[8];
            const int ka = kk ^ sa, kb = kk ^ sb;
            #pragma unroll
            for (int ri = 0; ri < 8; ++ri) a[ri] = tgL[(ty + 16 * ri) * 32 + ka];
            #pragma unroll
            for (int ci = 0; ci < 8; ++ci) b[ci] = pvL[(tx + 16 * ci) * 32 + kb];
            #pragma unroll
            for (int ri = 0; ri < 8; ++ri)
                #pragma unroll
                for (int ci = 0; ci < 8; ++ci) {
                    acc[ri][ci] += a[ri].x * b[ci].x;
                    acc[ri][ci] += a[ri].y * b[ci].y;
                    acc[ri][ci] += a[ri].z * b[ci].z;
                    acc[ri][ci] += a[ri].w * b[ci].w;
                }
        }
        #pragma unroll
        for (int ci = 0; ci < 8; ++ci) {
            const int jl = tx + 16 * ci;
            const int jg = j0 + jl;
            const float pj = p2L[jl];
            #pragma unroll
            for (int ri = 0; ri < 8; ++ri) {
                const float d = pj - 2.f * acc[ri][ci];
                if (d < minval[ri]) { minval[ri] = d; minidx[ri] = jg; }
            }
        }
    }
    __syncthreads();
    float2* red = reinterpret_cast<float2*>(pvL);
    #pragma unroll
    for (int ri = 0; ri < 8; ++ri) {
        const int row = ty + 16 * ri;
        red[row * 16 + tx] = make_float2(minval[ri], __int_as_float(minidx[ri]));
    }
    __syncthreads();
    if (t < TM) {
        float bv = INFINITY; int bi = 0x7fffffff;
        #pragma unroll
        for (int e = 0; e < 16; ++e) {
            const float2 p = red[t * 16 + e];
            const int pi = __float_as_int(p.y);
            if (p.x < bv || (p.x == bv && pi < bi)) { bv = p.x; bi = pi; }
        }
        partial[(size_t)(rowTile * TM + t) * FNCHUNK + chunk] =
            make_float2(bv, __int_as_float(bi));
    }
}

__global__ __launch_bounds__(256) void k_final_fb(
    const float* __restrict__ tg, const float* __restrict__ rg,
    const float* __restrict__ prev, const float2* __restrict__ partial,
    float* __restrict__ out_vals, float* __restrict__ out_grads)
{
    const int wave = threadIdx.x >> 6, lane = threadIdx.x & 63;
    const int i = blockIdx.x * 4 + wave;
    float bv = INFINITY; int bi = 0x7fffffff;
    if (lane < FNCHUNK) {
        const float2 p = partial[(size_t)i * FNCHUNK + lane];
        bv = p.x; bi = __float_as_int(p.y);
    }
    #pragma unroll
    for (int m = 1; m < 16; m <<= 1) {
        const float ov = __shfl_xor(bv, m);
        const int   oi = __shfl_xor(bi, m);
        if (ov < bv || (ov == bv && oi < bi)) { bv = ov; bi = oi; }
    }
    bi = __shfl(bi, 0);
    const float2 g = *reinterpret_cast<const float2*>(tg   + (size_t)i  * DIM + 2 * lane);
    const float2 s = *reinterpret_cast<const float2*>(prev + (size_t)bi * DIM + 2 * lane);
    const float2 r = *reinterpret_cast<const float2*>(rg   + (size_t)i  * DIM + 2 * lane);
    const float dsx = g.x - s.x, dsy = g.y - s.y;
    const float drx = g.x - r.x, dry = g.y - r.y;
    float ds = dsx * dsx + dsy * dsy;
    float dr = drx * drx + dry * dry;
    #pragma unroll
    for (int m = 1; m < 64; m <<= 1) { ds += __shfl_xor(ds, m); dr += __shfl_xor(dr, m); }
    const float sds = sqrtf(ds), sdr = sqrtf(dr);
    if (lane == 0) out_vals[i] = sds - sdr;
    const float is = 1.0f / sds, ir = 1.0f / sdr;
    float2 gr;
    gr.x = dsx * is - drx * ir;
    gr.y = dsy * is - dry * ir;
    *reinterpret_cast<float2*>(out_grads + (size_t)i * DIM + 2 * lane) = gr;
}

extern "C" void kernel_launch(void* const* d_in, const int* in_sizes, int n_in,
                              void* d_out, int out_size, void* d_ws, size_t ws_size,
                              hipStream_t stream) {
    const float* target  = (const float*)d_in[0];
    const float* reached = (const float*)d_in[1];
    const int n_total = in_sizes[0] / DIM;
    const int nprev = n_total - BATCH;

    const float* tg   = target  + (size_t)nprev * DIM;
    const float* rg   = reached + (size_t)nprev * DIM;
    const float* prev = reached;

    float* out_vals  = (float*)d_out;
    float* out_grads = out_vals + BATCH;

    const size_t offB  = 0;                       // 32 MiB (65536*256 bf16)
    const size_t offA  = (size_t)NPREV * 256 * 2; // 1 MiB  (2048*256 bf16)
    const size_t offP2 = offA + (size_t)BATCH * 256 * 2;
    const size_t offPt = offP2 + (size_t)NPREV * 4;
    const size_t need  = offPt + (size_t)BATCH * NCHUNKS * sizeof(float2);

    if (nprev == NPREV && ws_size >= need) {
        unsigned short* Bb = (unsigned short*)((char*)d_ws + offB);
        unsigned short* Ab = (unsigned short*)((char*)d_ws + offA);
        float*  prev2      = (float*)((char*)d_ws + offP2);
        float2* partial    = (float2*)((char*)d_ws + offPt);

        k_conv<<<(NPREV * 32) / 256, 256, 0, stream>>>(prev, Bb, NPREV * 32);
        k_conv<<<(BATCH * 32) / 256, 256, 0, stream>>>(tg, Ab, BATCH * 32);
        k_prev2<<<NPREV / 4, 256, 0, stream>>>(prev, prev2, NPREV);
        dim3 ggrid(16, NCHUNKS);
        k_gemm_argmin<<<ggrid, 256, 0, stream>>>(Ab, Bb, prev2, partial);
        k_final2<<<BATCH / 4, 256, 0, stream>>>(tg, rg, prev, partial, out_vals, out_grads);
    } else {
        float*  prev2   = (float*)d_ws;
        float2* partial = (float2*)((char*)d_ws + (size_t)nprev * sizeof(float));
        k_prev2<<<nprev / 4, 256, 0, stream>>>(prev, prev2, nprev);
        dim3 grid(BATCH / TM, FNCHUNK);
        k_argmin_fb<<<grid, 256, 0, stream>>>(tg, prev, prev2, partial);
        k_final_fb<<<BATCH / 4, 256, 0, stream>>>(tg, rg, prev, partial, out_vals, out_grads);
    }
}

// Round 3
// 112.453 us; speedup vs baseline: 4.6754x; 2.3402x over previous
//
#include <hip/hip_runtime.h>
#include <math.h>

#define DIM 128
#define BATCH 2048
#define NPREV 65536
#define NCH 32          // column chunks (grid.y)
#define NJT 8           // 256-col n-tiles per chunk
#define NKT 4           // virtual k-tiles of 64: A{hi0,hi1,lo0,lo1} x B{hi0,hi1,hi0,hi1}
#define NIT (NJT*NKT)
#define DELTA 0.25f

typedef __attribute__((ext_vector_type(8))) short bf16x8;
typedef __attribute__((ext_vector_type(4))) float f32x4;
typedef unsigned short u16;

static __device__ __forceinline__ unsigned short f2bf(float f) {
    unsigned int u = __float_as_uint(f);
    u += 0x7FFF + ((u >> 16) & 1);          // RTNE
    return (unsigned short)(u >> 16);
}
static __device__ __forceinline__ float bf2f(unsigned short h) {
    return __uint_as_float(((unsigned int)h) << 16);
}

#define GLOAD16(g, l) __builtin_amdgcn_global_load_lds( \
    (const __attribute__((address_space(1))) void*)(g), \
    (__attribute__((address_space(3))) void*)(l), 16, 0, 0)

// ---------- prev2[j] = ||prev_j||^2 ----------
__global__ __launch_bounds__(256) void k_prev2(const float* __restrict__ prev,
                                               float* __restrict__ prev2,
                                               int nprev) {
    const int wave = threadIdx.x >> 6;
    const int lane = threadIdx.x & 63;
    const int row = blockIdx.x * 4 + wave;
    if (row >= nprev) return;
    const float2 v = *reinterpret_cast<const float2*>(prev + (size_t)row * DIM + 2 * lane);
    float s = v.x * v.x + v.y * v.y;
    #pragma unroll
    for (int m = 1; m < 64; m <<= 1) s += __shfl_xor(s, m);
    if (lane == 0) prev2[row] = s;
}

// ---------- conversion into pre-tiled, pre-swizzled 32KB k-tile images ----------
// image layout (16B chunks): c = ks2*1024 + row*4 + slot; data = k-octet (slot ^ ((row>>1)&3))
// B: 2 hi images per 256-row n-tile (cols 0:64, 64:128)
__global__ __launch_bounds__(256) void k_convB(const float* __restrict__ src,
                                               u16* __restrict__ dst) {
    int id = blockIdx.x * 256 + threadIdx.x;          // 512 imgs * 2048 chunks
    int img = id >> 11, c = id & 2047;
    int ks2 = c >> 10, rem = c & 1023, row = rem >> 2, slot = rem & 3;
    int koct = slot ^ ((row >> 1) & 3);
    int srow = (img >> 1) * 256 + row;
    int scol = (img & 1) * 64 + ks2 * 32 + koct * 8;
    const float* s = src + (size_t)srow * DIM + scol;
    float4 f0 = *reinterpret_cast<const float4*>(s);
    float4 f1 = *reinterpret_cast<const float4*>(s + 4);
    float f[8] = {f0.x, f0.y, f0.z, f0.w, f1.x, f1.y, f1.z, f1.w};
    union { unsigned short us[8]; uint4 v; } o;
    #pragma unroll
    for (int e = 0; e < 8; ++e) o.us[e] = f2bf(f[e]);
    *reinterpret_cast<uint4*>(dst + (size_t)id * 8) = o.v;
}

// A: 4 images per 256-row m-tile: {hi(0:64), hi(64:128), lo(0:64), lo(64:128)}
__global__ __launch_bounds__(256) void k_convA(const float* __restrict__ src,
                                               u16* __restrict__ dst) {
    int id = blockIdx.x * 256 + threadIdx.x;          // 32 imgs * 2048 chunks
    int img = id >> 11, c = id & 2047;
    int ks2 = c >> 10, rem = c & 1023, row = rem >> 2, slot = rem & 3;
    int koct = slot ^ ((row >> 1) & 3);
    int a = img & 3;
    int srow = (img >> 2) * 256 + row;
    int scol = (a & 1) * 64 + ks2 * 32 + koct * 8;
    const float* s = src + (size_t)srow * DIM + scol;
    float4 f0 = *reinterpret_cast<const float4*>(s);
    float4 f1 = *reinterpret_cast<const float4*>(s + 4);
    float f[8] = {f0.x, f0.y, f0.z, f0.w, f1.x, f1.y, f1.z, f1.w};
    union { unsigned short us[8]; uint4 v; } o;
    if (a < 2) {
        #pragma unroll
        for (int e = 0; e < 8; ++e) o.us[e] = f2bf(f[e]);
    } else {
        #pragma unroll
        for (int e = 0; e < 8; ++e) {
            unsigned short h = f2bf(f[e]);
            o.us[e] = f2bf(f[e] - bf2f(h));
        }
    }
    *reinterpret_cast<uint4*>(dst + (size_t)id * 8) = o.v;
}

// ---------- 256x256 MFMA GEMM (virtual K=256) + in-register top-2 argmin ----------
// grid (8 mtiles, 32 chunks), 512 threads = 8 waves (4M x 2N), wave tile 64x128
__global__ __launch_bounds__(512, 2) void k_gemm_argmin(
    const u16* __restrict__ Aimg, const u16* __restrict__ Bimg,
    const float* __restrict__ prev2, float4* __restrict__ partial)
{
    __shared__ __align__(16) u16 At[2][16384];   // 64 KB
    __shared__ __align__(16) u16 Bt[2][16384];   // 64 KB

    const int t = threadIdx.x;
    const int lane = t & 63;
    const int w = t >> 6;
    const int wm = w >> 1;          // 0..3  (64-row band)
    const int wn = w & 1;           // 0..1  (128-col band)
    const int l15 = lane & 15;
    const int mtile = blockIdx.x;
    const int chunk = blockIdx.y;

    const int o16 = (w * 64 + lane) * 8;                       // staging offset (u16 units)
    const int sbyte = ((lane >> 4) ^ ((l15 >> 1) & 3)) << 4;   // swizzled slot byte
    const int abase = (wm * 64 + l15) * 64 + sbyte;
    const int bbase = (wn * 128 + l15) * 64 + sbyte;

    float v1[4][4], v2[4][4]; int j1[4][4], j2[4][4];
    #pragma unroll
    for (int fm = 0; fm < 4; ++fm)
        #pragma unroll
        for (int r = 0; r < 4; ++r) {
            v1[fm][r] = INFINITY; v2[fm][r] = INFINITY;
            j1[fm][r] = 0x7fffffff; j2[fm][r] = 0x7fffffff;
        }

    f32x4 acc[4][8];

    // prologue: stage it=0 into buf0
    {
        const u16* ga = Aimg + (size_t)(mtile * 4) * 16384;
        const u16* gb = Bimg + (size_t)(chunk * NJT) * 2 * 16384;
        #pragma unroll
        for (int c = 0; c < 4; ++c) {
            GLOAD16(ga + c * 4096 + o16, &At[0][c * 4096 + o16]);
            GLOAD16(gb + c * 4096 + o16, &Bt[0][c * 4096 + o16]);
        }
    }

    for (int it = 0; it < NIT; ++it) {
        const int kt = it & 3, jt = it >> 2;
        const int cur = it & 1;
        __syncthreads();                       // staged buf[cur] ready; prior reads of buf[cur^1] done
        if (it + 1 < NIT) {
            const int kt2 = (it + 1) & 3, jt2 = (it + 1) >> 2;
            const u16* ga = Aimg + (size_t)(mtile * 4 + kt2) * 16384;
            const u16* gb = Bimg + ((size_t)(chunk * NJT + jt2) * 2 + (kt2 & 1)) * 16384;
            u16* la = At[cur ^ 1]; u16* lb = Bt[cur ^ 1];
            #pragma unroll
            for (int c = 0; c < 4; ++c) {
                GLOAD16(ga + c * 4096 + o16, la + c * 4096 + o16);
                GLOAD16(gb + c * 4096 + o16, lb + c * 4096 + o16);
            }
        }
        if (kt == 0) {
            #pragma unroll
            for (int fm = 0; fm < 4; ++fm)
                #pragma unroll
                for (int fn = 0; fn < 8; ++fn)
                    acc[fm][fn] = (f32x4){0.f, 0.f, 0.f, 0.f};
        }
        const char* Ac = (const char*)At[cur];
        const char* Bc = (const char*)Bt[cur];
        #pragma unroll
        for (int ks2 = 0; ks2 < 2; ++ks2) {
            bf16x8 af[4], bf[8];
            #pragma unroll
            for (int fm = 0; fm < 4; ++fm)
                af[fm] = *(const bf16x8*)(Ac + abase + fm * 1024 + ks2 * 16384);
            #pragma unroll
            for (int fn = 0; fn < 8; ++fn)
                bf[fn] = *(const bf16x8*)(Bc + bbase + fn * 1024 + ks2 * 16384);
            #pragma unroll
            for (int fm = 0; fm < 4; ++fm)
                #pragma unroll
                for (int fn = 0; fn < 8; ++fn)
                    acc[fm][fn] = __builtin_amdgcn_mfma_f32_16x16x32_bf16(
                        af[fm], bf[fn], acc[fm][fn], 0, 0, 0);
        }
        if (kt == 3) {
            // barrier-free epilogue: d = prev2[j] - 2*dot; fn-tournament then top-2 insert
            const int ntile = chunk * NJT + jt;
            float p2f[8];
            #pragma unroll
            for (int fn = 0; fn < 8; ++fn)
                p2f[fn] = prev2[ntile * 256 + wn * 128 + fn * 16 + l15];
            const int jb = ntile * 256 + wn * 128 + l15;
            #pragma unroll
            for (int fm = 0; fm < 4; ++fm) {
                #pragma unroll
                for (int r = 0; r < 4; ++r) {
                    float dmin = p2f[0] - 2.f * acc[fm][0][r]; int fs = 0;
                    #pragma unroll
                    for (int fn = 1; fn < 8; ++fn) {
                        float d = p2f[fn] - 2.f * acc[fm][fn][r];
                        if (d < dmin) { dmin = d; fs = fn; }
                    }
                    const int j = jb + fs * 16;
                    const bool c1 = dmin < v1[fm][r];
                    const bool c2 = dmin < v2[fm][r];
                    v2[fm][r] = c1 ? v1[fm][r] : (c2 ? dmin : v2[fm][r]);
                    j2[fm][r] = c1 ? j1[fm][r] : (c2 ? j    : j2[fm][r]);
                    v1[fm][r] = c1 ? dmin : v1[fm][r];
                    j1[fm][r] = c1 ? j    : j1[fm][r];
                }
            }
        }
    }

    // ---- final: top-2 merge across 16-lane groups, then across wn, write partial ----
    float4* red = (float4*)At;                 // [256 rows][2 wn], 8 KB (buf1 idle)
    #pragma unroll
    for (int fm = 0; fm < 4; ++fm) {
        #pragma unroll
        for (int r = 0; r < 4; ++r) {
            float a1 = v1[fm][r], a2 = v2[fm][r];
            int   b1 = j1[fm][r], b2 = j2[fm][r];
            #pragma unroll
            for (int m = 1; m < 16; m <<= 1) {
                float o1 = __shfl_xor(a1, m); int p1 = __shfl_xor(b1, m);
                float o2 = __shfl_xor(a2, m); int p2 = __shfl_xor(b2, m);
                bool a = (o1 < a1) || (o1 == a1 && p1 < b1);
                float c1v = a ? a1 : o1; int c1j = a ? b1 : p1;
                float c2v = a ? o2 : a2; int c2j = a ? p2 : b2;
                float w1  = a ? o1 : a1; int k1  = a ? p1 : b1;
                bool b = (c1v < c2v) || (c1v == c2v && c1j < c2j);
                a1 = w1; b1 = k1;
                a2 = b ? c1v : c2v; b2 = b ? c1j : c2j;
            }
            if (l15 == 0) {
                int row = wm * 64 + fm * 16 + (lane >> 4) * 4 + r;
                red[row * 2 + wn] = make_float4(a1, __int_as_float(b1),
                                                a2, __int_as_float(b2));
            }
        }
    }
    __syncthreads();
    if (t < 256) {
        float4 x = red[t * 2 + 0], y = red[t * 2 + 1];
        float a1 = x.x, a2 = x.z; int b1 = __float_as_int(x.y), b2 = __float_as_int(x.w);
        float o1 = y.x, o2 = y.z; int p1 = __float_as_int(y.y), p2 = __float_as_int(y.w);
        bool a = (o1 < a1) || (o1 == a1 && p1 < b1);
        float c1v = a ? a1 : o1; int c1j = a ? b1 : p1;
        float c2v = a ? o2 : a2; int c2j = a ? p2 : b2;
        float w1  = a ? o1 : a1; int k1  = a ? p1 : b1;
        bool b = (c1v < c2v) || (c1v == c2v && c1j < c2j);
        partial[(size_t)(mtile * 256 + t) * NCH + chunk] =
            make_float4(w1, __int_as_float(k1),
                        b ? c1v : c2v, __int_as_float(b ? c1j : c2j));
    }
}

// ---------- final: global reduce + exact fp32 recheck + LP vals/grads ----------
__global__ __launch_bounds__(256) void k_final2(
    const float* __restrict__ tg, const float* __restrict__ rg,
    const float* __restrict__ prev, const float2* __restrict__ partial2,
    float* __restrict__ out_vals, float* __restrict__ out_grads)
{
    const int wv = threadIdx.x >> 6, lane = threadIdx.x & 63;
    const int i = blockIdx.x * 4 + wv;
    const float2 e = partial2[(size_t)i * 64 + lane];   // [32 chunks][2 entries]
    const float v = e.x; const int j = __float_as_int(e.y);

    float bv = v; int bj = j;
    #pragma unroll
    for (int m = 1; m < 64; m <<= 1) {
        float ov = __shfl_xor(bv, m); int oj = __shfl_xor(bj, m);
        if (ov < bv || (ov == bv && oj < bj)) { bv = ov; bj = oj; }
    }

    unsigned long long mask = __ballot(v <= bv + DELTA);
    const float2 g = *reinterpret_cast<const float2*>(tg + (size_t)i * DIM + 2 * lane);

    float bestd = INFINITY; int bestj = 0x7fffffff;
    while (mask) {
        int src = __ffsll(mask) - 1; mask &= mask - 1;
        int cj = __shfl(j, src);
        const float2 p = *reinterpret_cast<const float2*>(prev + (size_t)cj * DIM + 2 * lane);
        float dx = g.x - p.x, dy = g.y - p.y;
        float d = dx * dx + dy * dy;
        #pragma unroll
        for (int m = 1; m < 64; m <<= 1) d += __shfl_xor(d, m);
        if (d < bestd || (d == bestd && cj < bestj)) { bestd = d; bestj = cj; }
    }

    const float2 s = *reinterpret_cast<const float2*>(prev + (size_t)bestj * DIM + 2 * lane);
    const float2 r = *reinterpret_cast<const float2*>(rg + (size_t)i * DIM + 2 * lane);
    const float dsx = g.x - s.x, dsy = g.y - s.y;
    const float drx = g.x - r.x, dry = g.y - r.y;
    float ds = dsx * dsx + dsy * dsy;
    float dr = drx * drx + dry * dry;
    #pragma unroll
    for (int m = 1; m < 64; m <<= 1) { ds += __shfl_xor(ds, m); dr += __shfl_xor(dr, m); }
    const float sds = sqrtf(ds), sdr = sqrtf(dr);
    if (lane == 0) out_vals[i] = sds - sdr;
    const float is = 1.0f / sds, ir = 1.0f / sdr;
    float2 gr;
    gr.x = dsx * is - drx * ir;
    gr.y = dsy * is - dry * ir;
    *reinterpret_cast<float2*>(out_grads + (size_t)i * DIM + 2 * lane) = gr;
}

// ================= fallback (round-1 verified fp32 path) =================
#define TM 128
#define TN 128
#define FNCHUNK 16
#define JT_PER_CHUNK 32

__global__ __launch_bounds__(256, 1) void k_argmin_fb(
    const float* __restrict__ tg, const float* __restrict__ prev,
    const float* __restrict__ prev2, float2* __restrict__ partial)
{
    __shared__ float4 tgL[TM * 32];
    __shared__ float4 pvL[TN * 32];
    __shared__ float  p2L[TN];
    const int t = threadIdx.x;
    const int rowTile = blockIdx.x;
    const int chunk = blockIdx.y;
    const float4* tgG = reinterpret_cast<const float4*>(tg + (size_t)rowTile * TM * DIM);
    #pragma unroll
    for (int i = 0; i < 16; ++i) {
        const int idx = t + 256 * i;
        const int row = idx >> 5, kk = idx & 31;
        tgL[row * 32 + (kk ^ (row & 7))] = tgG[idx];
    }
    const int tx = t & 15, ty = t >> 4;
    const int sa = ty & 7, sb = tx & 7;
    float minval[8]; int minidx[8];
    #pragma unroll
    for (int ri = 0; ri < 8; ++ri) { minval[ri] = INFINITY; minidx[ri] = 0x7fffffff; }
    const int jchunk0 = chunk * (JT_PER_CHUNK * TN);
    for (int jt = 0; jt < JT_PER_CHUNK; ++jt) {
        const int j0 = jchunk0 + jt * TN;
        __syncthreads();
        const float4* pvG = reinterpret_cast<const float4*>(prev + (size_t)j0 * DIM);
        #pragma unroll
        for (int i = 0; i < 16; ++i) {
            const int idx = t + 256 * i;
            const int row = idx >> 5, kk = idx & 31;
            pvL[row * 32 + (kk ^ (row & 7))] = pvG[idx];
        }
        if (t < TN) p2L[t] = prev2[j0 + t];
        __syncthreads();
        float acc[8][8];
        #pragma unroll
        for (int ri = 0; ri < 8; ++ri)
            #pragma unroll
            for (int ci = 0; ci < 8; ++ci) acc[ri][ci] = 0.f;
        #pragma unroll 2
        for (int kk = 0; kk < 32; ++kk) {
            float4 a[8], b[8];
            const int ka = kk ^ sa, kb = kk ^ sb;
            #pragma unroll
            for (int ri = 0; ri < 8; ++ri) a[ri] = tgL[(ty + 16 * ri) * 32 + ka];
            #pragma unroll
            for (int ci = 0; ci < 8; ++ci) b[ci] = pvL[(tx + 16 * ci) * 32 + kb];
            #pragma unroll
            for (int ri = 0; ri < 8; ++ri)
                #pragma unroll
                for (int ci = 0; ci < 8; ++ci) {
                    acc[ri][ci] += a[ri].x * b[ci].x;
                    acc[ri][ci] += a[ri].y * b[ci].y;
                    acc[ri][ci] += a[ri].z * b[ci].z;
                    acc[ri][ci] += a[ri].w * b[ci].w;
                }
        }
        #pragma unroll
        for (int ci = 0; ci < 8; ++ci) {
            const int jl = tx + 16 * ci;
            const int jg = j0 + jl;
            const float pj = p2L[jl];
            #pragma unroll
            for (int ri = 0; ri < 8; ++ri) {
                const float d = pj - 2.f * acc[ri][ci];
                if (d < minval[ri]) { minval[ri] = d; minidx[ri] = jg; }
            }
        }
    }
    __syncthreads();
    float2* red = reinterpret_cast<float2*>(pvL);
    #pragma unroll
    for (int ri = 0; ri < 8; ++ri) {
        const int row = ty + 16 * ri;
        red[row * 16 + tx] = make_float2(minval[ri], __int_as_float(minidx[ri]));
    }
    __syncthreads();
    if (t < TM) {
        float bv = INFINITY; int bi = 0x7fffffff;
        #pragma unroll
        for (int e = 0; e < 16; ++e) {
            const float2 p = red[t * 16 + e];
            const int pi = __float_as_int(p.y);
            if (p.x < bv || (p.x == bv && pi < bi)) { bv = p.x; bi = pi; }
        }
        partial[(size_t)(rowTile * TM + t) * FNCHUNK + chunk] =
            make_float2(bv, __int_as_float(bi));
    }
}

__global__ __launch_bounds__(256) void k_final_fb(
    const float* __restrict__ tg, const float* __restrict__ rg,
    const float* __restrict__ prev, const float2* __restrict__ partial,
    float* __restrict__ out_vals, float* __restrict__ out_grads)
{
    const int wave = threadIdx.x >> 6, lane = threadIdx.x & 63;
    const int i = blockIdx.x * 4 + wave;
    float bv = INFINITY; int bi = 0x7fffffff;
    if (lane < FNCHUNK) {
        const float2 p = partial[(size_t)i * FNCHUNK + lane];
        bv = p.x; bi = __float_as_int(p.y);
    }
    #pragma unroll
    for (int m = 1; m < 16; m <<= 1) {
        const float ov = __shfl_xor(bv, m);
        const int   oi = __shfl_xor(bi, m);
        if (ov < bv || (ov == bv && oi < bi)) { bv = ov; bi = oi; }
    }
    bi = __shfl(bi, 0);
    const float2 g = *reinterpret_cast<const float2*>(tg   + (size_t)i  * DIM + 2 * lane);
    const float2 s = *reinterpret_cast<const float2*>(prev + (size_t)bi * DIM + 2 * lane);
    const float2 r = *reinterpret_cast<const float2*>(rg   + (size_t)i  * DIM + 2 * lane);
    const float dsx = g.x - s.x, dsy = g.y - s.y;
    const float drx = g.x - r.x, dry = g.y - r.y;
    float ds = dsx * dsx + dsy * dsy;
    float dr = drx * drx + dry * dry;
    #pragma unroll
    for (int m = 1; m < 64; m <<= 1) { ds += __shfl_xor(ds, m); dr += __shfl_xor(dr, m); }
    const float sds = sqrtf(ds), sdr = sqrtf(dr);
    if (lane == 0) out_vals[i] = sds - sdr;
    const float is = 1.0f / sds, ir = 1.0f / sdr;
    float2 gr;
    gr.x = dsx * is - drx * ir;
    gr.y = dsy * is - dry * ir;
    *reinterpret_cast<float2*>(out_grads + (size_t)i * DIM + 2 * lane) = gr;
}

extern "C" void kernel_launch(void* const* d_in, const int* in_sizes, int n_in,
                              void* d_out, int out_size, void* d_ws, size_t ws_size,
                              hipStream_t stream) {
    const float* target  = (const float*)d_in[0];
    const float* reached = (const float*)d_in[1];
    const int n_total = in_sizes[0] / DIM;
    const int nprev = n_total - BATCH;

    const float* tg   = target  + (size_t)nprev * DIM;
    const float* rg   = reached + (size_t)nprev * DIM;
    const float* prev = reached;

    float* out_vals  = (float*)d_out;
    float* out_grads = out_vals + BATCH;

    const size_t offB  = 0;                                   // 16 MiB (512 imgs)
    const size_t offA  = (size_t)512 * 16384 * 2;             // 1 MiB  (32 imgs)
    const size_t offP2 = offA + (size_t)32 * 16384 * 2;
    const size_t offPt = offP2 + (size_t)NPREV * 4;
    const size_t need  = offPt + (size_t)BATCH * NCH * sizeof(float4);

    if (nprev == NPREV && ws_size >= need) {
        u16*    Bb      = (u16*)((char*)d_ws + offB);
        u16*    Ab      = (u16*)((char*)d_ws + offA);
        float*  prev2   = (float*)((char*)d_ws + offP2);
        float4* partial = (float4*)((char*)d_ws + offPt);

        k_convB<<<(512 * 2048) / 256, 256, 0, stream>>>(prev, Bb);
        k_convA<<<(32 * 2048) / 256, 256, 0, stream>>>(tg, Ab);
        k_prev2<<<NPREV / 4, 256, 0, stream>>>(prev, prev2, NPREV);
        dim3 ggrid(8, NCH);
        k_gemm_argmin<<<ggrid, 512, 0, stream>>>(Ab, Bb, prev2, partial);
        k_final2<<<BATCH / 4, 256, 0, stream>>>(tg, rg, prev, (const float2*)partial,
                                                out_vals, out_grads);
    } else {
        float*  prev2   = (float*)d_ws;
        float2* partial = (float2*)((char*)d_ws + (size_t)nprev * sizeof(float));
        k_prev2<<<nprev / 4, 256, 0, stream>>>(prev, prev2, nprev);
        dim3 grid(BATCH / TM, FNCHUNK);
        k_argmin_fb<<<grid, 256, 0, stream>>>(tg, prev, prev2, partial);
        k_final_fb<<<BATCH / 4, 256, 0, stream>>>(tg, rg, prev, partial, out_vals, out_grads);
    }
}

// Round 4
// 82.820 us; speedup vs baseline: 6.3482x; 1.3578x over previous
//
#include <hip/hip_runtime.h>
#include <math.h>

#define DIM 128
#define BATCH 2048
#define NPREV 65536
#define NCH 32          // column chunks (grid "y")
#define NJT 16          // 128-col n-tiles per chunk
#define DELTA 0.25f

typedef __attribute__((ext_vector_type(8))) short bf16x8;
typedef __attribute__((ext_vector_type(4))) float f32x4;
typedef unsigned short u16;

static __device__ __forceinline__ unsigned short f2bf(float f) {
    unsigned int u = __float_as_uint(f);
    u += 0x7FFF + ((u >> 16) & 1);          // RTNE
    return (unsigned short)(u >> 16);
}
static __device__ __forceinline__ float bf2f(unsigned short h) {
    return __uint_as_float(((unsigned int)h) << 16);
}

#define GLOAD16(g, l) __builtin_amdgcn_global_load_lds( \
    (const __attribute__((address_space(1))) void*)(g), \
    (__attribute__((address_space(3))) void*)(l), 16, 0, 0)

// ---------- convB: bf16-hi images (pre-swizzled) + prev2 partials ----------
// 1024 imgs (2 per 128-col n-tile), each 16KB = 1024 chunks of 16B:
// c = ks2*512 + row*4 + slot; data = k-octet (slot ^ ((row>>1)&3))
__global__ __launch_bounds__(256) void k_convB(const float* __restrict__ src,
                                               u16* __restrict__ dst,
                                               float* __restrict__ p2part) {
    int id = blockIdx.x * 256 + threadIdx.x;      // 1024 * 1024
    int img = id >> 10, c = id & 1023;
    int ks2 = c >> 9, rem = c & 511, row = rem >> 2, slot = rem & 3;
    int koct = slot ^ ((row >> 1) & 3);
    int srow = (img >> 1) * 128 + row;
    int scol = (img & 1) * 64 + ks2 * 32 + koct * 8;
    const float* s = src + (size_t)srow * DIM + scol;
    float4 f0 = *reinterpret_cast<const float4*>(s);
    float4 f1 = *reinterpret_cast<const float4*>(s + 4);
    float f[8] = {f0.x, f0.y, f0.z, f0.w, f1.x, f1.y, f1.z, f1.w};
    union { unsigned short us[8]; uint4 v; } o;
    float sum = 0.f;
    #pragma unroll
    for (int e = 0; e < 8; ++e) { o.us[e] = f2bf(f[e]); sum += f[e] * f[e]; }
    *reinterpret_cast<uint4*>(dst + (size_t)id * 8) = o.v;
    p2part[srow * 16 + (scol >> 3)] = sum;
}

// ---------- prev2 reduce from partials (deterministic fixed order) ----------
__global__ __launch_bounds__(256) void k_prev2r(const float* __restrict__ p2part,
                                                float* __restrict__ prev2) {
    int row = blockIdx.x * 256 + threadIdx.x;
    const float4* p = reinterpret_cast<const float4*>(p2part + (size_t)row * 16);
    float4 a = p[0], b = p[1], c = p[2], d = p[3];
    float s = ((a.x + a.y) + (a.z + a.w)) + ((b.x + b.y) + (b.z + b.w))
            + ((c.x + c.y) + (c.z + c.w)) + ((d.x + d.y) + (d.z + d.w));
    prev2[row] = s;
}

// ---------- convA: 4 images per 256-row m-tile {hi0,hi1,lo0,lo1}, UNswizzled ----------
// img chunk c = ks2*1024 + row*4 + koct  (32KB per image)
__global__ __launch_bounds__(256) void k_convA(const float* __restrict__ src,
                                               u16* __restrict__ dst) {
    int id = blockIdx.x * 256 + threadIdx.x;      // 32 * 2048
    int img = id >> 11, c = id & 2047;
    int ks2 = c >> 10, rem = c & 1023, row = rem >> 2, koct = rem & 3;
    int a = img & 3;
    int srow = (img >> 2) * 256 + row;
    int scol = (a & 1) * 64 + ks2 * 32 + koct * 8;
    const float* s = src + (size_t)srow * DIM + scol;
    float4 f0 = *reinterpret_cast<const float4*>(s);
    float4 f1 = *reinterpret_cast<const float4*>(s + 4);
    float f[8] = {f0.x, f0.y, f0.z, f0.w, f1.x, f1.y, f1.z, f1.w};
    union { unsigned short us[8]; uint4 v; } o;
    if (a < 2) {
        #pragma unroll
        for (int e = 0; e < 8; ++e) o.us[e] = f2bf(f[e]);
    } else {
        #pragma unroll
        for (int e = 0; e < 8; ++e) {
            unsigned short h = f2bf(f[e]);
            o.us[e] = f2bf(f[e] - bf2f(h));
        }
    }
    *reinterpret_cast<uint4*>(dst + (size_t)id * 8) = o.v;
}

// ---------- main: A-in-register MFMA GEMM (256x128 tile, virtual K=256) ----------
// grid = 256 (1/CU), 512 threads = 8 waves, wave tile 32x128.
// XCD-bijective decode keeps all 8 mtile-blocks of a chunk on one XCD.
__global__ __launch_bounds__(512, 2) void k_gemm_argmin(
    const u16* __restrict__ Aimg, const u16* __restrict__ Bimg,
    const float* __restrict__ prev2, float4* __restrict__ partial)
{
    __shared__ __align__(16) u16 Bt[2][16384];   // 2 x 32 KB (double-buffered jt tile)

    const int t = threadIdx.x;
    const int lane = t & 63;
    const int w = t >> 6;            // 0..7: 32-row band
    const int l15 = lane & 15;
    const int lhi = lane >> 4;       // 0..3

    const int bid = blockIdx.x;
    const int mtile = bid >> 5;
    const int chunk = (bid & 7) + ((bid >> 3) & 3) * 8;   // chunk % 8 == bid % 8

    const u16* gb0 = Bimg + (size_t)chunk * NJT * 16384;

    // prologue: stage jt=0 into buf0
    #pragma unroll
    for (int c = 0; c < 4; ++c)
        GLOAD16(gb0 + c * 4096 + t * 8, &Bt[0][c * 4096 + t * 8]);

    // A into registers: areg[kt][ks2][fm] (64 VGPRs)
    bf16x8 areg[4][2][2];
    {
        const u16* ab = Aimg + (size_t)mtile * 4 * 16384;
        #pragma unroll
        for (int kt = 0; kt < 4; ++kt)
            #pragma unroll
            for (int ks2 = 0; ks2 < 2; ++ks2)
                #pragma unroll
                for (int fm = 0; fm < 2; ++fm) {
                    int row = w * 32 + fm * 16 + l15;
                    areg[kt][ks2][fm] = *reinterpret_cast<const bf16x8*>(
                        ab + (size_t)kt * 16384 + (ks2 * 1024 + row * 4 + lhi) * 8);
                }
    }

    const int bbase = l15 * 64 + ((lhi ^ ((l15 >> 1) & 3)) << 4);  // swizzled byte offset

    float v1[2][4], v2[2][4]; int j1_[2][4], j2_[2][4];
    #pragma unroll
    for (int fm = 0; fm < 2; ++fm)
        #pragma unroll
        for (int r = 0; r < 4; ++r) {
            v1[fm][r] = INFINITY; v2[fm][r] = INFINITY;
            j1_[fm][r] = 0x7fffffff; j2_[fm][r] = 0x7fffffff;
        }

    for (int jt = 0; jt < NJT; ++jt) {
        const int p = jt & 1;
        __syncthreads();              // buf[p] staged; buf[p^1] reads done
        if (jt + 1 < NJT) {
            const u16* gb = gb0 + (size_t)(jt + 1) * 16384;
            u16* lb = Bt[p ^ 1];
            #pragma unroll
            for (int c = 0; c < 4; ++c)
                GLOAD16(gb + c * 4096 + t * 8, lb + c * 4096 + t * 8);
        }
        float p2f[8];
        #pragma unroll
        for (int fn = 0; fn < 8; ++fn)
            p2f[fn] = prev2[chunk * 2048 + jt * 128 + fn * 16 + l15];

        f32x4 acc[2][8];
        #pragma unroll
        for (int fm = 0; fm < 2; ++fm)
            #pragma unroll
            for (int fn = 0; fn < 8; ++fn)
                acc[fm][fn] = (f32x4){0.f, 0.f, 0.f, 0.f};

        const char* Bc = (const char*)Bt[p];
        #pragma unroll
        for (int img = 0; img < 2; ++img) {
            #pragma unroll
            for (int ks2 = 0; ks2 < 2; ++ks2) {
                bf16x8 bf[8];
                #pragma unroll
                for (int fn = 0; fn < 8; ++fn)
                    bf[fn] = *reinterpret_cast<const bf16x8*>(
                        Bc + img * 16384 + ks2 * 8192 + fn * 1024 + bbase);
                // hi part (kt = img), then lo part (kt = img+2) share the B fragments
                #pragma unroll
                for (int fm = 0; fm < 2; ++fm)
                    #pragma unroll
                    for (int fn = 0; fn < 8; ++fn)
                        acc[fm][fn] = __builtin_amdgcn_mfma_f32_16x16x32_bf16(
                            areg[img][ks2][fm], bf[fn], acc[fm][fn], 0, 0, 0);
                #pragma unroll
                for (int fm = 0; fm < 2; ++fm)
                    #pragma unroll
                    for (int fn = 0; fn < 8; ++fn)
                        acc[fm][fn] = __builtin_amdgcn_mfma_f32_16x16x32_bf16(
                            areg[img + 2][ks2][fm], bf[fn], acc[fm][fn], 0, 0, 0);
            }
        }

        // epilogue: d = prev2[j] - 2*dot; fn tournament + per-lane top-2 insert
        const int jb = chunk * 2048 + jt * 128 + l15;
        #pragma unroll
        for (int fm = 0; fm < 2; ++fm) {
            #pragma unroll
            for (int r = 0; r < 4; ++r) {
                float dmin = p2f[0] - 2.f * acc[fm][0][r]; int fs = 0;
                #pragma unroll
                for (int fn = 1; fn < 8; ++fn) {
                    float d = p2f[fn] - 2.f * acc[fm][fn][r];
                    if (d < dmin) { dmin = d; fs = fn; }
                }
                const int j = jb + fs * 16;
                const bool c1 = dmin < v1[fm][r];
                const bool c2 = dmin < v2[fm][r];
                v2[fm][r] = c1 ? v1[fm][r] : (c2 ? dmin : v2[fm][r]);
                j2_[fm][r] = c1 ? j1_[fm][r] : (c2 ? j    : j2_[fm][r]);
                v1[fm][r] = c1 ? dmin : v1[fm][r];
                j1_[fm][r] = c1 ? j    : j1_[fm][r];
            }
        }
    }

    // final: 16-lane butterfly top-2 merge, lane l15==0 writes partial directly
    #pragma unroll
    for (int fm = 0; fm < 2; ++fm) {
        #pragma unroll
        for (int r = 0; r < 4; ++r) {
            float a1 = v1[fm][r], a2 = v2[fm][r];
            int   b1 = j1_[fm][r], b2 = j2_[fm][r];
            #pragma unroll
            for (int m = 1; m < 16; m <<= 1) {
                float o1 = __shfl_xor(a1, m); int p1 = __shfl_xor(b1, m);
                float o2 = __shfl_xor(a2, m); int p2 = __shfl_xor(b2, m);
                bool a = (o1 < a1) || (o1 == a1 && p1 < b1);
                float c1v = a ? a1 : o1; int c1j = a ? b1 : p1;
                float c2v = a ? o2 : a2; int c2j = a ? p2 : b2;
                float w1  = a ? o1 : a1; int k1  = a ? p1 : b1;
                bool b = (c1v < c2v) || (c1v == c2v && c1j < c2j);
                a1 = w1; b1 = k1;
                a2 = b ? c1v : c2v; b2 = b ? c1j : c2j;
            }
            if (l15 == 0) {
                int row = w * 32 + fm * 16 + lhi * 4 + r;
                partial[(size_t)(mtile * 256 + row) * NCH + chunk] =
                    make_float4(a1, __int_as_float(b1), a2, __int_as_float(b2));
            }
        }
    }
}

// ---------- final: global reduce + exact fp32 recheck + LP vals/grads ----------
__global__ __launch_bounds__(256) void k_final2(
    const float* __restrict__ tg, const float* __restrict__ rg,
    const float* __restrict__ prev, const float2* __restrict__ partial2,
    float* __restrict__ out_vals, float* __restrict__ out_grads)
{
    const int wv = threadIdx.x >> 6, lane = threadIdx.x & 63;
    const int i = blockIdx.x * 4 + wv;
    const float2 e = partial2[(size_t)i * 64 + lane];   // [32 chunks][2 entries]
    const float v = e.x; const int j = __float_as_int(e.y);

    float bv = v; int bj = j;
    #pragma unroll
    for (int m = 1; m < 64; m <<= 1) {
        float ov = __shfl_xor(bv, m); int oj = __shfl_xor(bj, m);
        if (ov < bv || (ov == bv && oj < bj)) { bv = ov; bj = oj; }
    }

    unsigned long long mask = __ballot(v <= bv + DELTA);
    const float2 g = *reinterpret_cast<const float2*>(tg + (size_t)i * DIM + 2 * lane);

    float bestd = INFINITY; int bestj = 0x7fffffff;
    while (mask) {
        int src = __ffsll(mask) - 1; mask &= mask - 1;
        int cj = __shfl(j, src);
        const float2 p = *reinterpret_cast<const float2*>(prev + (size_t)cj * DIM + 2 * lane);
        float dx = g.x - p.x, dy = g.y - p.y;
        float d = dx * dx + dy * dy;
        #pragma unroll
        for (int m = 1; m < 64; m <<= 1) d += __shfl_xor(d, m);
        if (d < bestd || (d == bestd && cj < bestj)) { bestd = d; bestj = cj; }
    }

    const float2 s = *reinterpret_cast<const float2*>(prev + (size_t)bestj * DIM + 2 * lane);
    const float2 r = *reinterpret_cast<const float2*>(rg + (size_t)i * DIM + 2 * lane);
    const float dsx = g.x - s.x, dsy = g.y - s.y;
    const float drx = g.x - r.x, dry = g.y - r.y;
    float ds = dsx * dsx + dsy * dsy;
    float dr = drx * drx + dry * dry;
    #pragma unroll
    for (int m = 1; m < 64; m <<= 1) { ds += __shfl_xor(ds, m); dr += __shfl_xor(dr, m); }
    const float sds = sqrtf(ds), sdr = sqrtf(dr);
    if (lane == 0) out_vals[i] = sds - sdr;
    const float is = 1.0f / sds, ir = 1.0f / sdr;
    float2 gr;
    gr.x = dsx * is - drx * ir;
    gr.y = dsy * is - dry * ir;
    *reinterpret_cast<float2*>(out_grads + (size_t)i * DIM + 2 * lane) = gr;
}

// ================= fallback (round-1 verified fp32 path) =================
#define TM 128
#define TN 128
#define FNCHUNK 16
#define JT_PER_CHUNK 32

__global__ __launch_bounds__(256) void k_prev2(const float* __restrict__ prev,
                                               float* __restrict__ prev2,
                                               int nprev) {
    const int wave = threadIdx.x >> 6;
    const int lane = threadIdx.x & 63;
    const int row = blockIdx.x * 4 + wave;
    if (row >= nprev) return;
    const float2 v = *reinterpret_cast<const float2*>(prev + (size_t)row * DIM + 2 * lane);
    float s = v.x * v.x + v.y * v.y;
    #pragma unroll
    for (int m = 1; m < 64; m <<= 1) s += __shfl_xor(s, m);
    if (lane == 0) prev2[row] = s;
}

__global__ __launch_bounds__(256, 1) void k_argmin_fb(
    const float* __restrict__ tg, const float* __restrict__ prev,
    const float* __restrict__ prev2, float2* __restrict__ partial)
{
    __shared__ float4 tgL[TM * 32];
    __shared__ float4 pvL[TN * 32];
    __shared__ float  p2L[TN];
    const int t = threadIdx.x;
    const int rowTile = blockIdx.x;
    const int chunk = blockIdx.y;
    const float4* tgG = reinterpret_cast<const float4*>(tg + (size_t)rowTile * TM * DIM);
    #pragma unroll
    for (int i = 0; i < 16; ++i) {
        const int idx = t + 256 * i;
        const int row = idx >> 5, kk = idx & 31;
        tgL[row * 32 + (kk ^ (row & 7))] = tgG[idx];
    }
    const int tx = t & 15, ty = t >> 4;
    const int sa = ty & 7, sb = tx & 7;
    float minval[8]; int minidx[8];
    #pragma unroll
    for (int ri = 0; ri < 8; ++ri) { minval[ri] = INFINITY; minidx[ri] = 0x7fffffff; }
    const int jchunk0 = chunk * (JT_PER_CHUNK * TN);
    for (int jt = 0; jt < JT_PER_CHUNK; ++jt) {
        const int j0 = jchunk0 + jt * TN;
        __syncthreads();
        const float4* pvG = reinterpret_cast<const float4*>(prev + (size_t)j0 * DIM);
        #pragma unroll
        for (int i = 0; i < 16; ++i) {
            const int idx = t + 256 * i;
            const int row = idx >> 5, kk = idx & 31;
            pvL[row * 32 + (kk ^ (row & 7))] = pvG[idx];
        }
        if (t < TN) p2L[t] = prev2[j0 + t];
        __syncthreads();
        float acc[8][8];
        #pragma unroll
        for (int ri = 0; ri < 8; ++ri)
            #pragma unroll
            for (int ci = 0; ci < 8; ++ci) acc[ri][ci] = 0.f;
        #pragma unroll 2
        for (int kk = 0; kk < 32; ++kk) {
            float4 a[8], b[8];
            const int ka = kk ^ sa, kb = kk ^ sb;
            #pragma unroll
            for (int ri = 0; ri < 8; ++ri) a[ri] = tgL[(ty + 16 * ri) * 32 + ka];
            #pragma unroll
            for (int ci = 0; ci < 8; ++ci) b[ci] = pvL[(tx + 16 * ci) * 32 + kb];
            #pragma unroll
            for (int ri = 0; ri < 8; ++ri)
                #pragma unroll
                for (int ci = 0; ci < 8; ++ci) {
                    acc[ri][ci] += a[ri].x * b[ci].x;
                    acc[ri][ci] += a[ri].y * b[ci].y;
                    acc[ri][ci] += a[ri].z * b[ci].z;
                    acc[ri][ci] += a[ri].w * b[ci].w;
                }
        }
        #pragma unroll
        for (int ci = 0; ci < 8; ++ci) {
            const int jl = tx + 16 * ci;
            const int jg = j0 + jl;
            const float pj = p2L[jl];
            #pragma unroll
            for (int ri = 0; ri < 8; ++ri) {
                const float d = pj - 2.f * acc[ri][ci];
                if (d < minval[ri]) { minval[ri] = d; minidx[ri] = jg; }
            }
        }
    }
    __syncthreads();
    float2* red = reinterpret_cast<float2*>(pvL);
    #pragma unroll
    for (int ri = 0; ri < 8; ++ri) {
        const int row = ty + 16 * ri;
        red[row * 16 + tx] = make_float2(minval[ri], __int_as_float(minidx[ri]));
    }
    __syncthreads();
    if (t < TM) {
        float bv = INFINITY; int bi = 0x7fffffff;
        #pragma unroll
        for (int e = 0; e < 16; ++e) {
            const float2 p = red[t * 16 + e];
            const int pi = __float_as_int(p.y);
            if (p.x < bv || (p.x == bv && pi < bi)) { bv = p.x; bi = pi; }
        }
        partial[(size_t)(rowTile * TM + t) * FNCHUNK + chunk] =
            make_float2(bv, __int_as_float(bi));
    }
}

__global__ __launch_bounds__(256) void k_final_fb(
    const float* __restrict__ tg, const float* __restrict__ rg,
    const float* __restrict__ prev, const float2* __restrict__ partial,
    float* __restrict__ out_vals, float* __restrict__ out_grads)
{
    const int wave = threadIdx.x >> 6, lane = threadIdx.x & 63;
    const int i = blockIdx.x * 4 + wave;
    float bv = INFINITY; int bi = 0x7fffffff;
    if (lane < FNCHUNK) {
        const float2 p = partial[(size_t)i * FNCHUNK + lane];
        bv = p.x; bi = __float_as_int(p.y);
    }
    #pragma unroll
    for (int m = 1; m < 16; m <<= 1) {
        const float ov = __shfl_xor(bv, m);
        const int   oi = __shfl_xor(bi, m);
        if (ov < bv || (ov == bv && oi < bi)) { bv = ov; bi = oi; }
    }
    bi = __shfl(bi, 0);
    const float2 g = *reinterpret_cast<const float2*>(tg   + (size_t)i  * DIM + 2 * lane);
    const float2 s = *reinterpret_cast<const float2*>(prev + (size_t)bi * DIM + 2 * lane);
    const float2 r = *reinterpret_cast<const float2*>(rg   + (size_t)i  * DIM + 2 * lane);
    const float dsx = g.x - s.x, dsy = g.y - s.y;
    const float drx = g.x - r.x, dry = g.y - r.y;
    float ds = dsx * dsx + dsy * dsy;
    float dr = drx * drx + dry * dry;
    #pragma unroll
    for (int m = 1; m < 64; m <<= 1) { ds += __shfl_xor(ds, m); dr += __shfl_xor(dr, m); }
    const float sds = sqrtf(ds), sdr = sqrtf(dr);
    if (lane == 0) out_vals[i] = sds - sdr;
    const float is = 1.0f / sds, ir = 1.0f / sdr;
    float2 gr;
    gr.x = dsx * is - drx * ir;
    gr.y = dsy * is - dry * ir;
    *reinterpret_cast<float2*>(out_grads + (size_t)i * DIM + 2 * lane) = gr;
}

extern "C" void kernel_launch(void* const* d_in, const int* in_sizes, int n_in,
                              void* d_out, int out_size, void* d_ws, size_t ws_size,
                              hipStream_t stream) {
    const float* target  = (const float*)d_in[0];
    const float* reached = (const float*)d_in[1];
    const int n_total = in_sizes[0] / DIM;
    const int nprev = n_total - BATCH;

    const float* tg   = target  + (size_t)nprev * DIM;
    const float* rg   = reached + (size_t)nprev * DIM;
    const float* prev = reached;

    float* out_vals  = (float*)d_out;
    float* out_grads = out_vals + BATCH;

    const size_t offB  = 0;                                 // 16 MiB (1024 x 16KB imgs)
    const size_t offA  = (size_t)1024 * 8192 * 2;           // 1 MiB  (32 x 32KB imgs)
    const size_t offP2 = offA + (size_t)32 * 16384 * 2;     // 256 KiB
    const size_t offPP = offP2 + (size_t)NPREV * 4;         // 4 MiB  (p2 partials)
    const size_t offPt = offPP + (size_t)NPREV * 16 * 4;    // 1 MiB  (partial top-2)
    const size_t need  = offPt + (size_t)BATCH * NCH * sizeof(float4);

    if (nprev == NPREV && ws_size >= need) {
        u16*    Bb      = (u16*)((char*)d_ws + offB);
        u16*    Ab      = (u16*)((char*)d_ws + offA);
        float*  prev2   = (float*)((char*)d_ws + offP2);
        float*  p2part  = (float*)((char*)d_ws + offPP);
        float4* partial = (float4*)((char*)d_ws + offPt);

        k_convB<<<(1024 * 1024) / 256, 256, 0, stream>>>(prev, Bb, p2part);
        k_convA<<<(32 * 2048) / 256, 256, 0, stream>>>(tg, Ab);
        k_prev2r<<<NPREV / 256, 256, 0, stream>>>(p2part, prev2);
        k_gemm_argmin<<<256, 512, 0, stream>>>(Ab, Bb, prev2, partial);
        k_final2<<<BATCH / 4, 256, 0, stream>>>(tg, rg, prev, (const float2*)partial,
                                                out_vals, out_grads);
    } else {
        float*  prev2   = (float*)d_ws;
        float2* partial = (float2*)((char*)d_ws + (size_t)nprev * sizeof(float));
        k_prev2<<<nprev / 4, 256, 0, stream>>>(prev, prev2, nprev);
        dim3 grid(BATCH / TM, FNCHUNK);
        k_argmin_fb<<<grid, 256, 0, stream>>>(tg, prev, prev2, partial);
        k_final_fb<<<BATCH / 4, 256, 0, stream>>>(tg, rg, prev, partial, out_vals, out_grads);
    }
}

// Round 5
// 67.619 us; speedup vs baseline: 7.7753x; 1.2248x over previous
//
#include <hip/hip_runtime.h>
#include <math.h>

#define DIM 128
#define BATCH 2048
#define NPREV 65536
#define NCH 32          // column chunks
#define NJT 16          // 128-col n-tiles per chunk
#define DELTA 0.4f

typedef __attribute__((ext_vector_type(8))) short bf16x8;
typedef __attribute__((ext_vector_type(4))) float f32x4;
typedef unsigned short u16;

static __device__ __forceinline__ unsigned short f2bf(float f) {
    unsigned int u = __float_as_uint(f);
    u += 0x7FFF + ((u >> 16) & 1);          // RTNE
    return (unsigned short)(u >> 16);
}

#define GLOAD16(g, l) __builtin_amdgcn_global_load_lds( \
    (const __attribute__((address_space(1))) void*)(g), \
    (__attribute__((address_space(3))) void*)(l), 16, 0, 0)

// ---------- convB: bf16-hi images (pre-swizzled) + prev2 partials ----------
// 1024 imgs (2 k-halves per 128-col n-tile), each 16KB = 1024 chunks of 16B:
// c = ks2*512 + row*4 + slot; data = k-octet (slot ^ ((row>>1)&3))
__global__ __launch_bounds__(256) void k_convB(const float* __restrict__ src,
                                               u16* __restrict__ dst,
                                               float* __restrict__ p2part) {
    int id = blockIdx.x * 256 + threadIdx.x;      // 1024 * 1024
    int img = id >> 10, c = id & 1023;
    int ks2 = c >> 9, rem = c & 511, row = rem >> 2, slot = rem & 3;
    int koct = slot ^ ((row >> 1) & 3);
    int srow = (img >> 1) * 128 + row;
    int scol = (img & 1) * 64 + ks2 * 32 + koct * 8;
    const float* s = src + (size_t)srow * DIM + scol;
    float4 f0 = *reinterpret_cast<const float4*>(s);
    float4 f1 = *reinterpret_cast<const float4*>(s + 4);
    float f[8] = {f0.x, f0.y, f0.z, f0.w, f1.x, f1.y, f1.z, f1.w};
    union { unsigned short us[8]; uint4 v; } o;
    float sum = 0.f;
    #pragma unroll
    for (int e = 0; e < 8; ++e) { o.us[e] = f2bf(f[e]); sum += f[e] * f[e]; }
    *reinterpret_cast<uint4*>(dst + (size_t)id * 8) = o.v;
    p2part[srow * 16 + (scol >> 3)] = sum;
}

// ---------- prev2 reduce from partials (deterministic fixed order) ----------
__global__ __launch_bounds__(256) void k_prev2r(const float* __restrict__ p2part,
                                                float* __restrict__ prev2) {
    int row = blockIdx.x * 256 + threadIdx.x;
    const float4* p = reinterpret_cast<const float4*>(p2part + (size_t)row * 16);
    float4 a = p[0], b = p[1], c = p[2], d = p[3];
    float s = ((a.x + a.y) + (a.z + a.w)) + ((b.x + b.y) + (b.z + b.w))
            + ((c.x + c.y) + (c.z + c.w)) + ((d.x + d.y) + (d.z + d.w));
    prev2[row] = s;
}

// ---------- convA: 2 hi images per 256-row m-tile {k 0:64, k 64:128}, UNswizzled ----------
// img chunk c = ks2*1024 + row*4 + koct  (32KB per image)
__global__ __launch_bounds__(256) void k_convA(const float* __restrict__ src,
                                               u16* __restrict__ dst) {
    int id = blockIdx.x * 256 + threadIdx.x;      // 16 * 2048 = 32768
    int img = id >> 11, c = id & 2047;
    int ks2 = c >> 10, rem = c & 1023, row = rem >> 2, koct = rem & 3;
    int srow = (img >> 1) * 256 + row;
    int scol = (img & 1) * 64 + ks2 * 32 + koct * 8;
    const float* s = src + (size_t)srow * DIM + scol;
    float4 f0 = *reinterpret_cast<const float4*>(s);
    float4 f1 = *reinterpret_cast<const float4*>(s + 4);
    float f[8] = {f0.x, f0.y, f0.z, f0.w, f1.x, f1.y, f1.z, f1.w};
    union { unsigned short us[8]; uint4 v; } o;
    #pragma unroll
    for (int e = 0; e < 8; ++e) o.us[e] = f2bf(f[e]);
    *reinterpret_cast<uint4*>(dst + (size_t)id * 8) = o.v;
}

// ---------- main: A-in-register MFMA GEMM (256x128 tile, K=128 screen) ----------
// grid = 256 (1/CU), 512 threads = 8 waves, wave tile 32x128.
// XCD-bijective decode keeps all 8 mtile-blocks of a chunk on one XCD.
__global__ __launch_bounds__(512, 2) void k_gemm_argmin(
    const u16* __restrict__ Aimg, const u16* __restrict__ Bimg,
    const float* __restrict__ prev2, float4* __restrict__ partial)
{
    __shared__ __align__(16) u16 Bt[2][16384];   // 2 x 32 KB (double-buffered jt tile)

    const int t = threadIdx.x;
    const int lane = t & 63;
    const int w = t >> 6;            // 0..7: 32-row band
    const int l15 = lane & 15;
    const int lhi = lane >> 4;       // 0..3

    const int bid = blockIdx.x;
    const int mtile = bid >> 5;
    const int chunk = (bid & 7) + ((bid >> 3) & 3) * 8;   // chunk % 8 == bid % 8

    const u16* gb0 = Bimg + (size_t)chunk * NJT * 16384;

    // prologue: stage jt=0 into buf0
    #pragma unroll
    for (int c = 0; c < 4; ++c)
        GLOAD16(gb0 + c * 4096 + t * 8, &Bt[0][c * 4096 + t * 8]);

    // A into registers: areg[kt][ks2][fm] (32 VGPRs)
    bf16x8 areg[2][2][2];
    {
        const u16* ab = Aimg + (size_t)mtile * 2 * 16384;
        #pragma unroll
        for (int kt = 0; kt < 2; ++kt)
            #pragma unroll
            for (int ks2 = 0; ks2 < 2; ++ks2)
                #pragma unroll
                for (int fm = 0; fm < 2; ++fm) {
                    int row = w * 32 + fm * 16 + l15;
                    areg[kt][ks2][fm] = *reinterpret_cast<const bf16x8*>(
                        ab + (size_t)kt * 16384 + (ks2 * 1024 + row * 4 + lhi) * 8);
                }
    }

    const int bbase = l15 * 64 + ((lhi ^ ((l15 >> 1) & 3)) << 4);  // swizzled byte offset
    const f32x4 z4 = {0.f, 0.f, 0.f, 0.f};

    float v1[2][4], v2[2][4]; int j1_[2][4], j2_[2][4];
    #pragma unroll
    for (int fm = 0; fm < 2; ++fm)
        #pragma unroll
        for (int r = 0; r < 4; ++r) {
            v1[fm][r] = INFINITY; v2[fm][r] = INFINITY;
            j1_[fm][r] = 0x7fffffff; j2_[fm][r] = 0x7fffffff;
        }

    for (int jt = 0; jt < NJT; ++jt) {
        const int p = jt & 1;
        __syncthreads();              // buf[p] staged; buf[p^1] reads done
        if (jt + 1 < NJT) {
            const u16* gb = gb0 + (size_t)(jt + 1) * 16384;
            u16* lb = Bt[p ^ 1];
            #pragma unroll
            for (int c = 0; c < 4; ++c)
                GLOAD16(gb + c * 4096 + t * 8, lb + c * 4096 + t * 8);
        }
        float p2f[8];
        #pragma unroll
        for (int fn = 0; fn < 8; ++fn)
            p2f[fn] = prev2[chunk * 2048 + jt * 128 + fn * 16 + l15];

        f32x4 acc[2][8];
        const char* Bc = (const char*)Bt[p];
        #pragma unroll
        for (int s = 0; s < 4; ++s) {
            const int img = s >> 1, ks2 = s & 1;
            bf16x8 bf[8];
            #pragma unroll
            for (int fn = 0; fn < 8; ++fn)
                bf[fn] = *reinterpret_cast<const bf16x8*>(
                    Bc + img * 16384 + ks2 * 8192 + fn * 1024 + bbase);
            if (s == 0) {
                #pragma unroll
                for (int fm = 0; fm < 2; ++fm)
                    #pragma unroll
                    for (int fn = 0; fn < 8; ++fn)
                        acc[fm][fn] = __builtin_amdgcn_mfma_f32_16x16x32_bf16(
                            areg[0][0][fm], bf[fn], z4, 0, 0, 0);
            } else {
                #pragma unroll
                for (int fm = 0; fm < 2; ++fm)
                    #pragma unroll
                    for (int fn = 0; fn < 8; ++fn)
                        acc[fm][fn] = __builtin_amdgcn_mfma_f32_16x16x32_bf16(
                            areg[img][ks2][fm], bf[fn], acc[fm][fn], 0, 0, 0);
            }
        }

        // epilogue: d = prev2[j] - 2*dot; fn tournament + per-lane top-2 insert
        const int jb = chunk * 2048 + jt * 128 + l15;
        #pragma unroll
        for (int fm = 0; fm < 2; ++fm) {
            #pragma unroll
            for (int r = 0; r < 4; ++r) {
                float dmin = p2f[0] - 2.f * acc[fm][0][r]; int fs = 0;
                #pragma unroll
                for (int fn = 1; fn < 8; ++fn) {
                    float d = p2f[fn] - 2.f * acc[fm][fn][r];
                    if (d < dmin) { dmin = d; fs = fn; }
                }
                const int j = jb + fs * 16;
                const bool c1 = dmin < v1[fm][r];
                const bool c2 = dmin < v2[fm][r];
                v2[fm][r] = c1 ? v1[fm][r] : (c2 ? dmin : v2[fm][r]);
                j2_[fm][r] = c1 ? j1_[fm][r] : (c2 ? j    : j2_[fm][r]);
                v1[fm][r] = c1 ? dmin : v1[fm][r];
                j1_[fm][r] = c1 ? j    : j1_[fm][r];
            }
        }
    }

    // final: 16-lane butterfly top-2 merge, lane l15==0 writes partial directly
    #pragma unroll
    for (int fm = 0; fm < 2; ++fm) {
        #pragma unroll
        for (int r = 0; r < 4; ++r) {
            float a1 = v1[fm][r], a2 = v2[fm][r];
            int   b1 = j1_[fm][r], b2 = j2_[fm][r];
            #pragma unroll
            for (int m = 1; m < 16; m <<= 1) {
                float o1 = __shfl_xor(a1, m); int p1 = __shfl_xor(b1, m);
                float o2 = __shfl_xor(a2, m); int p2 = __shfl_xor(b2, m);
                bool a = (o1 < a1) || (o1 == a1 && p1 < b1);
                float c1v = a ? a1 : o1; int c1j = a ? b1 : p1;
                float c2v = a ? o2 : a2; int c2j = a ? p2 : b2;
                float w1  = a ? o1 : a1; int k1  = a ? p1 : b1;
                bool b = (c1v < c2v) || (c1v == c2v && c1j < c2j);
                a1 = w1; b1 = k1;
                a2 = b ? c1v : c2v; b2 = b ? c1j : c2j;
            }
            if (l15 == 0) {
                int row = w * 32 + fm * 16 + lhi * 4 + r;
                partial[(size_t)(mtile * 256 + row) * NCH + chunk] =
                    make_float4(a1, __int_as_float(b1), a2, __int_as_float(b2));
            }
        }
    }
}

// ---------- final: global reduce + exact fp32 recheck + LP vals/grads ----------
__global__ __launch_bounds__(256) void k_final2(
    const float* __restrict__ tg, const float* __restrict__ rg,
    const float* __restrict__ prev, const float2* __restrict__ partial2,
    float* __restrict__ out_vals, float* __restrict__ out_grads)
{
    const int wv = threadIdx.x >> 6, lane = threadIdx.x & 63;
    const int i = blockIdx.x * 4 + wv;
    const float2 e = partial2[(size_t)i * 64 + lane];   // [32 chunks][2 entries]
    const float v = e.x; const int j = __float_as_int(e.y);

    float bv = v; int bj = j;
    #pragma unroll
    for (int m = 1; m < 64; m <<= 1) {
        float ov = __shfl_xor(bv, m); int oj = __shfl_xor(bj, m);
        if (ov < bv || (ov == bv && oj < bj)) { bv = ov; bj = oj; }
    }

    unsigned long long mask = __ballot(v <= bv + DELTA);
    const float2 g = *reinterpret_cast<const float2*>(tg + (size_t)i * DIM + 2 * lane);

    float bestd = INFINITY; int bestj = 0x7fffffff;
    while (mask) {
        int src = __ffsll(mask) - 1; mask &= mask - 1;
        int cj = __shfl(j, src);
        const float2 p = *reinterpret_cast<const float2*>(prev + (size_t)cj * DIM + 2 * lane);
        float dx = g.x - p.x, dy = g.y - p.y;
        float d = dx * dx + dy * dy;
        #pragma unroll
        for (int m = 1; m < 64; m <<= 1) d += __shfl_xor(d, m);
        if (d < bestd || (d == bestd && cj < bestj)) { bestd = d; bestj = cj; }
    }

    const float2 s = *reinterpret_cast<const float2*>(prev + (size_t)bestj * DIM + 2 * lane);
    const float2 r = *reinterpret_cast<const float2*>(rg + (size_t)i * DIM + 2 * lane);
    const float dsx = g.x - s.x, dsy = g.y - s.y;
    const float drx = g.x - r.x, dry = g.y - r.y;
    float ds = dsx * dsx + dsy * dsy;
    float dr = drx * drx + dry * dry;
    #pragma unroll
    for (int m = 1; m < 64; m <<= 1) { ds += __shfl_xor(ds, m); dr += __shfl_xor(dr, m); }
    const float sds = sqrtf(ds), sdr = sqrtf(dr);
    if (lane == 0) out_vals[i] = sds - sdr;
    const float is = 1.0f / sds, ir = 1.0f / sdr;
    float2 gr;
    gr.x = dsx * is - drx * ir;
    gr.y = dsy * is - dry * ir;
    *reinterpret_cast<float2*>(out_grads + (size_t)i * DIM + 2 * lane) = gr;
}

// ================= fallback (round-1 verified fp32 path) =================
#define TM 128
#define TN 128
#define FNCHUNK 16
#define JT_PER_CHUNK 32

__global__ __launch_bounds__(256) void k_prev2(const float* __restrict__ prev,
                                               float* __restrict__ prev2,
                                               int nprev) {
    const int wave = threadIdx.x >> 6;
    const int lane = threadIdx.x & 63;
    const int row = blockIdx.x * 4 + wave;
    if (row >= nprev) return;
    const float2 v = *reinterpret_cast<const float2*>(prev + (size_t)row * DIM + 2 * lane);
    float s = v.x * v.x + v.y * v.y;
    #pragma unroll
    for (int m = 1; m < 64; m <<= 1) s += __shfl_xor(s, m);
    if (lane == 0) prev2[row] = s;
}

__global__ __launch_bounds__(256, 1) void k_argmin_fb(
    const float* __restrict__ tg, const float* __restrict__ prev,
    const float* __restrict__ prev2, float2* __restrict__ partial)
{
    __shared__ float4 tgL[TM * 32];
    __shared__ float4 pvL[TN * 32];
    __shared__ float  p2L[TN];
    const int t = threadIdx.x;
    const int rowTile = blockIdx.x;
    const int chunk = blockIdx.y;
    const float4* tgG = reinterpret_cast<const float4*>(tg + (size_t)rowTile * TM * DIM);
    #pragma unroll
    for (int i = 0; i < 16; ++i) {
        const int idx = t + 256 * i;
        const int row = idx >> 5, kk = idx & 31;
        tgL[row * 32 + (kk ^ (row & 7))] = tgG[idx];
    }
    const int tx = t & 15, ty = t >> 4;
    const int sa = ty & 7, sb = tx & 7;
    float minval[8]; int minidx[8];
    #pragma unroll
    for (int ri = 0; ri < 8; ++ri) { minval[ri] = INFINITY; minidx[ri] = 0x7fffffff; }
    const int jchunk0 = chunk * (JT_PER_CHUNK * TN);
    for (int jt = 0; jt < JT_PER_CHUNK; ++jt) {
        const int j0 = jchunk0 + jt * TN;
        __syncthreads();
        const float4* pvG = reinterpret_cast<const float4*>(prev + (size_t)j0 * DIM);
        #pragma unroll
        for (int i = 0; i < 16; ++i) {
            const int idx = t + 256 * i;
            const int row = idx >> 5, kk = idx & 31;
            pvL[row * 32 + (kk ^ (row & 7))] = pvG[idx];
        }
        if (t < TN) p2L[t] = prev2[j0 + t];
        __syncthreads();
        float acc[8][8];
        #pragma unroll
        for (int ri = 0; ri < 8; ++ri)
            #pragma unroll
            for (int ci = 0; ci < 8; ++ci) acc[ri][ci] = 0.f;
        #pragma unroll 2
        for (int kk = 0; kk < 32; ++kk) {
            float4 a[8], b[8];
            const int ka = kk ^ sa, kb = kk ^ sb;
            #pragma unroll
            for (int ri = 0; ri < 8; ++ri) a[ri] = tgL[(ty + 16 * ri) * 32 + ka];
            #pragma unroll
            for (int ci = 0; ci < 8; ++ci) b[ci] = pvL[(tx + 16 * ci) * 32 + kb];
            #pragma unroll
            for (int ri = 0; ri < 8; ++ri)
                #pragma unroll
                for (int ci = 0; ci < 8; ++ci) {
                    acc[ri][ci] += a[ri].x * b[ci].x;
                    acc[ri][ci] += a[ri].y * b[ci].y;
                    acc[ri][ci] += a[ri].z * b[ci].z;
                    acc[ri][ci] += a[ri].w * b[ci].w;
                }
        }
        #pragma unroll
        for (int ci = 0; ci < 8; ++ci) {
            const int jl = tx + 16 * ci;
            const int jg = j0 + jl;
            const float pj = p2L[jl];
            #pragma unroll
            for (int ri = 0; ri < 8; ++ri) {
                const float d = pj - 2.f * acc[ri][ci];
                if (d < minval[ri]) { minval[ri] = d; minidx[ri] = jg; }
            }
        }
    }
    __syncthreads();
    float2* red = reinterpret_cast<float2*>(pvL);
    #pragma unroll
    for (int ri = 0; ri < 8; ++ri) {
        const int row = ty + 16 * ri;
        red[row * 16 + tx] = make_float2(minval[ri], __int_as_float(minidx[ri]));
    }
    __syncthreads();
    if (t < TM) {
        float bv = INFINITY; int bi = 0x7fffffff;
        #pragma unroll
        for (int e = 0; e < 16; ++e) {
            const float2 p = red[t * 16 + e];
            const int pi = __float_as_int(p.y);
            if (p.x < bv || (p.x == bv && pi < bi)) { bv = p.x; bi = pi; }
        }
        partial[(size_t)(rowTile * TM + t) * FNCHUNK + chunk] =
            make_float2(bv, __int_as_float(bi));
    }
}

__global__ __launch_bounds__(256) void k_final_fb(
    const float* __restrict__ tg, const float* __restrict__ rg,
    const float* __restrict__ prev, const float2* __restrict__ partial,
    float* __restrict__ out_vals, float* __restrict__ out_grads)
{
    const int wave = threadIdx.x >> 6, lane = threadIdx.x & 63;
    const int i = blockIdx.x * 4 + wave;
    float bv = INFINITY; int bi = 0x7fffffff;
    if (lane < FNCHUNK) {
        const float2 p = partial[(size_t)i * FNCHUNK + lane];
        bv = p.x; bi = __float_as_int(p.y);
    }
    #pragma unroll
    for (int m = 1; m < 16; m <<= 1) {
        const float ov = __shfl_xor(bv, m);
        const int   oi = __shfl_xor(bi, m);
        if (ov < bv || (ov == bv && oi < bi)) { bv = ov; bi = oi; }
    }
    bi = __shfl(bi, 0);
    const float2 g = *reinterpret_cast<const float2*>(tg   + (size_t)i  * DIM + 2 * lane);
    const float2 s = *reinterpret_cast<const float2*>(prev + (size_t)bi * DIM + 2 * lane);
    const float2 r = *reinterpret_cast<const float2*>(rg   + (size_t)i  * DIM + 2 * lane);
    const float dsx = g.x - s.x, dsy = g.y - s.y;
    const float drx = g.x - r.x, dry = g.y - r.y;
    float ds = dsx * dsx + dsy * dsy;
    float dr = drx * drx + dry * dry;
    #pragma unroll
    for (int m = 1; m < 64; m <<= 1) { ds += __shfl_xor(ds, m); dr += __shfl_xor(dr, m); }
    const float sds = sqrtf(ds), sdr = sqrtf(dr);
    if (lane == 0) out_vals[i] = sds - sdr;
    const float is = 1.0f / sds, ir = 1.0f / sdr;
    float2 gr;
    gr.x = dsx * is - drx * ir;
    gr.y = dsy * is - dry * ir;
    *reinterpret_cast<float2*>(out_grads + (size_t)i * DIM + 2 * lane) = gr;
}

extern "C" void kernel_launch(void* const* d_in, const int* in_sizes, int n_in,
                              void* d_out, int out_size, void* d_ws, size_t ws_size,
                              hipStream_t stream) {
    const float* target  = (const float*)d_in[0];
    const float* reached = (const float*)d_in[1];
    const int n_total = in_sizes[0] / DIM;
    const int nprev = n_total - BATCH;

    const float* tg   = target  + (size_t)nprev * DIM;
    const float* rg   = reached + (size_t)nprev * DIM;
    const float* prev = reached;

    float* out_vals  = (float*)d_out;
    float* out_grads = out_vals + BATCH;

    const size_t offB  = 0;                                 // 16 MiB (1024 x 16KB imgs)
    const size_t offA  = (size_t)1024 * 8192 * 2;           // 512 KiB (16 x 32KB imgs)
    const size_t offP2 = offA + (size_t)16 * 16384 * 2;     // 256 KiB
    const size_t offPP = offP2 + (size_t)NPREV * 4;         // 4 MiB  (p2 partials)
    const size_t offPt = offPP + (size_t)NPREV * 16 * 4;    // 1 MiB  (partial top-2)
    const size_t need  = offPt + (size_t)BATCH * NCH * sizeof(float4);

    if (nprev == NPREV && ws_size >= need) {
        u16*    Bb      = (u16*)((char*)d_ws + offB);
        u16*    Ab      = (u16*)((char*)d_ws + offA);
        float*  prev2   = (float*)((char*)d_ws + offP2);
        float*  p2part  = (float*)((char*)d_ws + offPP);
        float4* partial = (float4*)((char*)d_ws + offPt);

        k_convB<<<(1024 * 1024) / 256, 256, 0, stream>>>(prev, Bb, p2part);
        k_convA<<<(16 * 2048) / 256, 256, 0, stream>>>(tg, Ab);
        k_prev2r<<<NPREV / 256, 256, 0, stream>>>(p2part, prev2);
        k_gemm_argmin<<<256, 512, 0, stream>>>(Ab, Bb, prev2, partial);
        k_final2<<<BATCH / 4, 256, 0, stream>>>(tg, rg, prev, (const float2*)partial,
                                                out_vals, out_grads);
    } else {
        float*  prev2   = (float*)d_ws;
        float2* partial = (float2*)((char*)d_ws + (size_t)nprev * sizeof(float));
        k_prev2<<<nprev / 4, 256, 0, stream>>>(prev, prev2, nprev);
        dim3 grid(BATCH / TM, FNCHUNK);
        k_argmin_fb<<<grid, 256, 0, stream>>>(tg, prev, prev2, partial);
        k_final_fb<<<BATCH / 4, 256, 0, stream>>>(tg, rg, prev, partial, out_vals, out_grads);
    }
}

// Round 6
// 61.132 us; speedup vs baseline: 8.6004x; 1.1061x over previous
//
#include <hip/hip_runtime.h>
#include <math.h>

#define DIM 128
#define BATCH 2048
#define NPREV 65536
#define NCH 32          // column chunks
#define NJT 16          // 128-col n-tiles per chunk
#define DELTA 0.8f

typedef __attribute__((ext_vector_type(8))) short bf16x8;
typedef __attribute__((ext_vector_type(4))) float f32x4;
typedef unsigned short u16;

static __device__ __forceinline__ unsigned short f2bf(float f) {
    unsigned int u = __float_as_uint(f);
    u += 0x7FFF + ((u >> 16) & 1);          // RTNE
    return (unsigned short)(u >> 16);
}

#define GLOAD16(g, l) __builtin_amdgcn_global_load_lds( \
    (const __attribute__((address_space(1))) void*)(g), \
    (__attribute__((address_space(3))) void*)(l), 16, 0, 0)

// ---------- convB: bf16-hi images (pre-swizzled) + prev2 partials ----------
// 1024 imgs (2 k-halves per 128-col n-tile), each 16KB = 1024 chunks of 16B:
// c = ks2*512 + row*4 + slot; data = k-octet (slot ^ ((row>>1)&3))
__global__ __launch_bounds__(256) void k_convB(const float* __restrict__ src,
                                               u16* __restrict__ dst,
                                               float* __restrict__ p2part) {
    int id = blockIdx.x * 256 + threadIdx.x;      // 1024 * 1024
    int img = id >> 10, c = id & 1023;
    int ks2 = c >> 9, rem = c & 511, row = rem >> 2, slot = rem & 3;
    int koct = slot ^ ((row >> 1) & 3);
    int srow = (img >> 1) * 128 + row;
    int scol = (img & 1) * 64 + ks2 * 32 + koct * 8;
    const float* s = src + (size_t)srow * DIM + scol;
    float4 f0 = *reinterpret_cast<const float4*>(s);
    float4 f1 = *reinterpret_cast<const float4*>(s + 4);
    float f[8] = {f0.x, f0.y, f0.z, f0.w, f1.x, f1.y, f1.z, f1.w};
    union { unsigned short us[8]; uint4 v; } o;
    float sum = 0.f;
    #pragma unroll
    for (int e = 0; e < 8; ++e) { o.us[e] = f2bf(f[e]); sum += f[e] * f[e]; }
    *reinterpret_cast<uint4*>(dst + (size_t)id * 8) = o.v;
    p2part[srow * 16 + (scol >> 3)] = sum;
}

// ---------- prev2 reduce: p2h[j] = -0.5 * ||prev_j||^2 (deterministic order) ----------
__global__ __launch_bounds__(256) void k_prev2r(const float* __restrict__ p2part,
                                                float* __restrict__ p2h) {
    int row = blockIdx.x * 256 + threadIdx.x;
    const float4* p = reinterpret_cast<const float4*>(p2part + (size_t)row * 16);
    float4 a = p[0], b = p[1], c = p[2], d = p[3];
    float s = ((a.x + a.y) + (a.z + a.w)) + ((b.x + b.y) + (b.z + b.w))
            + ((c.x + c.y) + (c.z + c.w)) + ((d.x + d.y) + (d.z + d.w));
    p2h[row] = -0.5f * s;
}

// ---------- convA: 2 hi images per 256-row m-tile {k 0:64, k 64:128}, UNswizzled ----------
// img chunk c = ks2*1024 + row*4 + koct  (32KB per image)
__global__ __launch_bounds__(256) void k_convA(const float* __restrict__ src,
                                               u16* __restrict__ dst) {
    int id = blockIdx.x * 256 + threadIdx.x;      // 16 * 2048 = 32768
    int img = id >> 11, c = id & 2047;
    int ks2 = c >> 10, rem = c & 1023, row = rem >> 2, koct = rem & 3;
    int srow = (img >> 1) * 256 + row;
    int scol = (img & 1) * 64 + ks2 * 32 + koct * 8;
    const float* s = src + (size_t)srow * DIM + scol;
    float4 f0 = *reinterpret_cast<const float4*>(s);
    float4 f1 = *reinterpret_cast<const float4*>(s + 4);
    float f[8] = {f0.x, f0.y, f0.z, f0.w, f1.x, f1.y, f1.z, f1.w};
    union { unsigned short us[8]; uint4 v; } o;
    #pragma unroll
    for (int e = 0; e < 8; ++e) o.us[e] = f2bf(f[e]);
    *reinterpret_cast<uint4*>(dst + (size_t)id * 8) = o.v;
}

// ---------- main: 256x128 tile, K=128 screen, col-split waves, packed-key argmin ----------
// grid = 256 (1/CU), 512 threads = 8 waves (4 row-bands x 2 col-groups), wave = 64r x 64c.
// acc initialized with C = -prev2[j]/2 => d = -2*acc; argmin d == argmax acc.
// Key packs index in low 11 mantissa bits: [0:1]=fn [2:5]=l15 [6:9]=jt [10]=colgrp.
__global__ __launch_bounds__(512, 2) void k_gemm_argmin(
    const u16* __restrict__ Aimg, const u16* __restrict__ Bimg,
    const float* __restrict__ p2h, float4* __restrict__ partial)
{
    __shared__ __align__(16) u16 Bt[2][16384];   // 2 x 32 KB (double-buffered jt tile)

    const int t = threadIdx.x;
    const int lane = t & 63;
    const int w = t >> 6;
    const int wrow = w & 3;          // 0..3: 64-row band
    const int cg = w >> 2;           // 0..1: 64-col group
    const int l15 = lane & 15;
    const int lhi = lane >> 4;       // 0..3

    const int bid = blockIdx.x;
    const int mtile = bid >> 5;
    const int chunk = (bid & 7) + ((bid >> 3) & 3) * 8;   // XCD-bijective

    const u16* gb0 = Bimg + (size_t)chunk * NJT * 16384;

    // prologue: stage jt=0 into buf0
    #pragma unroll
    for (int c = 0; c < 4; ++c)
        GLOAD16(gb0 + c * 4096 + t * 8, &Bt[0][c * 4096 + t * 8]);

    // A into registers: areg[stage][fm] (64 VGPRs); stage = img*2 + ks2
    bf16x8 areg[4][4];
    {
        const u16* ab = Aimg + (size_t)mtile * 2 * 16384;
        #pragma unroll
        for (int s = 0; s < 4; ++s) {
            const int img = s >> 1, ks2 = s & 1;
            #pragma unroll
            for (int fm = 0; fm < 4; ++fm) {
                int row = wrow * 64 + fm * 16 + l15;
                areg[s][fm] = *reinterpret_cast<const bf16x8*>(
                    ab + (size_t)img * 16384 + (ks2 * 1024 + row * 4 + lhi) * 8);
            }
        }
    }

    const int sbyte = (lhi ^ ((l15 >> 1) & 3)) << 4;
    const int bbase = (cg * 64 + l15) * 64 + sbyte;      // byte offset in image
    const unsigned sbase = ((unsigned)cg << 10) | ((unsigned)l15 << 2);
    const int phbase = chunk * 2048 + cg * 64 + l15;

    float v1[4][4], v2[4][4];
    #pragma unroll
    for (int fm = 0; fm < 4; ++fm)
        #pragma unroll
        for (int r = 0; r < 4; ++r) { v1[fm][r] = -INFINITY; v2[fm][r] = -INFINITY; }

    // prefetch p2h for jt=0
    float phc[4];
    #pragma unroll
    for (int fn = 0; fn < 4; ++fn) phc[fn] = p2h[phbase + fn * 16];

    for (int jt = 0; jt < NJT; ++jt) {
        const int p = jt & 1;
        __syncthreads();              // buf[p] staged; buf[p^1] reads done
        if (jt + 1 < NJT) {
            const u16* gb = gb0 + (size_t)(jt + 1) * 16384;
            u16* lb = Bt[p ^ 1];
            #pragma unroll
            for (int c = 0; c < 4; ++c)
                GLOAD16(gb + c * 4096 + t * 8, lb + c * 4096 + t * 8);
        }
        float phn[4];
        if (jt + 1 < NJT) {
            #pragma unroll
            for (int fn = 0; fn < 4; ++fn)
                phn[fn] = p2h[phbase + (jt + 1) * 128 + fn * 16];
        }

        // acc init from C = -prev2/2 (kills epilogue fma)
        f32x4 acc[4][4];
        #pragma unroll
        for (int fn = 0; fn < 4; ++fn) {
            const float pv = phc[fn];
            #pragma unroll
            for (int fm = 0; fm < 4; ++fm)
                acc[fm][fn] = (f32x4){pv, pv, pv, pv};
        }

        const char* Bc = (const char*)Bt[p];
        #pragma unroll
        for (int s = 0; s < 4; ++s) {
            const int img = s >> 1, ks2 = s & 1;
            bf16x8 bf[4];
            #pragma unroll
            for (int fn = 0; fn < 4; ++fn)
                bf[fn] = *reinterpret_cast<const bf16x8*>(
                    Bc + img * 16384 + ks2 * 8192 + fn * 1024 + bbase);
            #pragma unroll
            for (int fm = 0; fm < 4; ++fm)
                #pragma unroll
                for (int fn = 0; fn < 4; ++fn)
                    acc[fm][fn] = __builtin_amdgcn_mfma_f32_16x16x32_bf16(
                        areg[s][fm], bf[fn], acc[fm][fn], 0, 0, 0);
        }

        // epilogue: packed-key 4-way max tree + branchless top-2 insert
        const unsigned stampv = sbase | ((unsigned)jt << 6);
        #pragma unroll
        for (int fm = 0; fm < 4; ++fm) {
            #pragma unroll
            for (int r = 0; r < 4; ++r) {
                unsigned u0 = (__float_as_uint(acc[fm][0][r]) & ~0x7FFu);
                unsigned u1 = (__float_as_uint(acc[fm][1][r]) & ~0x7FFu) | 1u;
                unsigned u2 = (__float_as_uint(acc[fm][2][r]) & ~0x7FFu) | 2u;
                unsigned u3 = (__float_as_uint(acc[fm][3][r]) & ~0x7FFu) | 3u;
                float m = fmaxf(fmaxf(__uint_as_float(u0), __uint_as_float(u1)),
                                fmaxf(__uint_as_float(u2), __uint_as_float(u3)));
                float key = __uint_as_float(__float_as_uint(m) | stampv);
                float tm = fminf(v1[fm][r], key);
                v1[fm][r] = fmaxf(v1[fm][r], key);
                v2[fm][r] = fmaxf(v2[fm][r], tm);
            }
        }

        if (jt + 1 < NJT) {
            #pragma unroll
            for (int fn = 0; fn < 4; ++fn) phc[fn] = phn[fn];
        }
    }

    // ---- butterfly top-2 merge over 16 lanes (keys carry index) ----
    float2* red = reinterpret_cast<float2*>(Bt);   // [256 rows][2 cg], 4 KB (safe: last jt reads Bt[1])
    #pragma unroll
    for (int fm = 0; fm < 4; ++fm) {
        #pragma unroll
        for (int r = 0; r < 4; ++r) {
            float a1 = v1[fm][r], a2 = v2[fm][r];
            #pragma unroll
            for (int m = 1; m < 16; m <<= 1) {
                float o1 = __shfl_xor(a1, m), o2 = __shfl_xor(a2, m);
                float n2 = fmaxf(fminf(a1, o1), fmaxf(a2, o2));
                a1 = fmaxf(a1, o1); a2 = n2;
            }
            if (l15 == 0) {
                int row = wrow * 64 + fm * 16 + lhi * 4 + r;
                red[row * 2 + cg] = make_float2(a1, a2);
            }
        }
    }
    __syncthreads();
    if (t < 256) {
        float2 x = red[t * 2 + 0], y = red[t * 2 + 1];
        float u1f = fmaxf(x.x, y.x);
        float u2f = fmaxf(fminf(x.x, y.x), fmaxf(x.y, y.y));
        unsigned ua = __float_as_uint(u1f), ub = __float_as_uint(u2f);
        int ja = chunk * 2048 + (int)((ua >> 6) & 15) * 128 + (int)((ua >> 10) & 1) * 64
               + (int)(ua & 3) * 16 + (int)((ua >> 2) & 15);
        int jb = chunk * 2048 + (int)((ub >> 6) & 15) * 128 + (int)((ub >> 10) & 1) * 64
               + (int)(ub & 3) * 16 + (int)((ub >> 2) & 15);
        float d1 = -2.0f * __uint_as_float(ua & ~0x7FFu);
        float d2 = -2.0f * __uint_as_float(ub & ~0x7FFu);
        partial[(size_t)(mtile * 256 + t) * NCH + chunk] =
            make_float4(d1, __int_as_float(ja), d2, __int_as_float(jb));
    }
}

// ---------- final: global reduce + exact fp32 recheck + LP vals/grads ----------
__global__ __launch_bounds__(256) void k_final2(
    const float* __restrict__ tg, const float* __restrict__ rg,
    const float* __restrict__ prev, const float2* __restrict__ partial2,
    float* __restrict__ out_vals, float* __restrict__ out_grads)
{
    const int wv = threadIdx.x >> 6, lane = threadIdx.x & 63;
    const int i = blockIdx.x * 4 + wv;
    const float2 e = partial2[(size_t)i * 64 + lane];   // [32 chunks][2 entries]
    const float v = e.x; const int j = __float_as_int(e.y);

    float bv = v; int bj = j;
    #pragma unroll
    for (int m = 1; m < 64; m <<= 1) {
        float ov = __shfl_xor(bv, m); int oj = __shfl_xor(bj, m);
        if (ov < bv || (ov == bv && oj < bj)) { bv = ov; bj = oj; }
    }

    unsigned long long mask = __ballot(v <= bv + DELTA);
    const float2 g = *reinterpret_cast<const float2*>(tg + (size_t)i * DIM + 2 * lane);

    float bestd = INFINITY; int bestj = 0x7fffffff;
    while (mask) {
        int src = __ffsll(mask) - 1; mask &= mask - 1;
        int cj = __shfl(j, src);
        const float2 p = *reinterpret_cast<const float2*>(prev + (size_t)cj * DIM + 2 * lane);
        float dx = g.x - p.x, dy = g.y - p.y;
        float d = dx * dx + dy * dy;
        #pragma unroll
        for (int m = 1; m < 64; m <<= 1) d += __shfl_xor(d, m);
        if (d < bestd || (d == bestd && cj < bestj)) { bestd = d; bestj = cj; }
    }

    const float2 s = *reinterpret_cast<const float2*>(prev + (size_t)bestj * DIM + 2 * lane);
    const float2 r = *reinterpret_cast<const float2*>(rg + (size_t)i * DIM + 2 * lane);
    const float dsx = g.x - s.x, dsy = g.y - s.y;
    const float drx = g.x - r.x, dry = g.y - r.y;
    float ds = dsx * dsx + dsy * dsy;
    float dr = drx * drx + dry * dry;
    #pragma unroll
    for (int m = 1; m < 64; m <<= 1) { ds += __shfl_xor(ds, m); dr += __shfl_xor(dr, m); }
    const float sds = sqrtf(ds), sdr = sqrtf(dr);
    if (lane == 0) out_vals[i] = sds - sdr;
    const float is = 1.0f / sds, ir = 1.0f / sdr;
    float2 gr;
    gr.x = dsx * is - drx * ir;
    gr.y = dsy * is - dry * ir;
    *reinterpret_cast<float2*>(out_grads + (size_t)i * DIM + 2 * lane) = gr;
}

// ================= fallback (round-1 verified fp32 path) =================
#define TM 128
#define TN 128
#define FNCHUNK 16
#define JT_PER_CHUNK 32

__global__ __launch_bounds__(256) void k_prev2(const float* __restrict__ prev,
                                               float* __restrict__ prev2,
                                               int nprev) {
    const int wave = threadIdx.x >> 6;
    const int lane = threadIdx.x & 63;
    const int row = blockIdx.x * 4 + wave;
    if (row >= nprev) return;
    const float2 v = *reinterpret_cast<const float2*>(prev + (size_t)row * DIM + 2 * lane);
    float s = v.x * v.x + v.y * v.y;
    #pragma unroll
    for (int m = 1; m < 64; m <<= 1) s += __shfl_xor(s, m);
    if (lane == 0) prev2[row] = s;
}

__global__ __launch_bounds__(256, 1) void k_argmin_fb(
    const float* __restrict__ tg, const float* __restrict__ prev,
    const float* __restrict__ prev2, float2* __restrict__ partial)
{
    __shared__ float4 tgL[TM * 32];
    __shared__ float4 pvL[TN * 32];
    __shared__ float  p2L[TN];
    const int t = threadIdx.x;
    const int rowTile = blockIdx.x;
    const int chunk = blockIdx.y;
    const float4* tgG = reinterpret_cast<const float4*>(tg + (size_t)rowTile * TM * DIM);
    #pragma unroll
    for (int i = 0; i < 16; ++i) {
        const int idx = t + 256 * i;
        const int row = idx >> 5, kk = idx & 31;
        tgL[row * 32 + (kk ^ (row & 7))] = tgG[idx];
    }
    const int tx = t & 15, ty = t >> 4;
    const int sa = ty & 7, sb = tx & 7;
    float minval[8]; int minidx[8];
    #pragma unroll
    for (int ri = 0; ri < 8; ++ri) { minval[ri] = INFINITY; minidx[ri] = 0x7fffffff; }
    const int jchunk0 = chunk * (JT_PER_CHUNK * TN);
    for (int jt = 0; jt < JT_PER_CHUNK; ++jt) {
        const int j0 = jchunk0 + jt * TN;
        __syncthreads();
        const float4* pvG = reinterpret_cast<const float4*>(prev + (size_t)j0 * DIM);
        #pragma unroll
        for (int i = 0; i < 16; ++i) {
            const int idx = t + 256 * i;
            const int row = idx >> 5, kk = idx & 31;
            pvL[row * 32 + (kk ^ (row & 7))] = pvG[idx];
        }
        if (t < TN) p2L[t] = prev2[j0 + t];
        __syncthreads();
        float acc[8][8];
        #pragma unroll
        for (int ri = 0; ri < 8; ++ri)
            #pragma unroll
            for (int ci = 0; ci < 8; ++ci) acc[ri][ci] = 0.f;
        #pragma unroll 2
        for (int kk = 0; kk < 32; ++kk) {
            float4 a[8], b[8];
            const int ka = kk ^ sa, kb = kk ^ sb;
            #pragma unroll
            for (int ri = 0; ri < 8; ++ri) a[ri] = tgL[(ty + 16 * ri) * 32 + ka];
            #pragma unroll
            for (int ci = 0; ci < 8; ++ci) b[ci] = pvL[(tx + 16 * ci) * 32 + kb];
            #pragma unroll
            for (int ri = 0; ri < 8; ++ri)
                #pragma unroll
                for (int ci = 0; ci < 8; ++ci) {
                    acc[ri][ci] += a[ri].x * b[ci].x;
                    acc[ri][ci] += a[ri].y * b[ci].y;
                    acc[ri][ci] += a[ri].z * b[ci].z;
                    acc[ri][ci] += a[ri].w * b[ci].w;
                }
        }
        #pragma unroll
        for (int ci = 0; ci < 8; ++ci) {
            const int jl = tx + 16 * ci;
            const int jg = j0 + jl;
            const float pj = p2L[jl];
            #pragma unroll
            for (int ri = 0; ri < 8; ++ri) {
                const float d = pj - 2.f * acc[ri][ci];
                if (d < minval[ri]) { minval[ri] = d; minidx[ri] = jg; }
            }
        }
    }
    __syncthreads();
    float2* red = reinterpret_cast<float2*>(pvL);
    #pragma unroll
    for (int ri = 0; ri < 8; ++ri) {
        const int row = ty + 16 * ri;
        red[row * 16 + tx] = make_float2(minval[ri], __int_as_float(minidx[ri]));
    }
    __syncthreads();
    if (t < TM) {
        float bv = INFINITY; int bi = 0x7fffffff;
        #pragma unroll
        for (int e = 0; e < 16; ++e) {
            const float2 p = red[t * 16 + e];
            const int pi = __float_as_int(p.y);
            if (p.x < bv || (p.x == bv && pi < bi)) { bv = p.x; bi = pi; }
        }
        partial[(size_t)(rowTile * TM + t) * FNCHUNK + chunk] =
            make_float2(bv, __int_as_float(bi));
    }
}

__global__ __launch_bounds__(256) void k_final_fb(
    const float* __restrict__ tg, const float* __restrict__ rg,
    const float* __restrict__ prev, const float2* __restrict__ partial,
    float* __restrict__ out_vals, float* __restrict__ out_grads)
{
    const int wave = threadIdx.x >> 6, lane = threadIdx.x & 63;
    const int i = blockIdx.x * 4 + wave;
    float bv = INFINITY; int bi = 0x7fffffff;
    if (lane < FNCHUNK) {
        const float2 p = partial[(size_t)i * FNCHUNK + lane];
        bv = p.x; bi = __float_as_int(p.y);
    }
    #pragma unroll
    for (int m = 1; m < 16; m <<= 1) {
        const float ov = __shfl_xor(bv, m);
        const int   oi = __shfl_xor(bi, m);
        if (ov < bv || (ov == bv && oi < bi)) { bv = ov; bi = oi; }
    }
    bi = __shfl(bi, 0);
    const float2 g = *reinterpret_cast<const float2*>(tg   + (size_t)i  * DIM + 2 * lane);
    const float2 s = *reinterpret_cast<const float2*>(prev + (size_t)bi * DIM + 2 * lane);
    const float2 r = *reinterpret_cast<const float2*>(rg   + (size_t)i  * DIM + 2 * lane);
    const float dsx = g.x - s.x, dsy = g.y - s.y;
    const float drx = g.x - r.x, dry = g.y - r.y;
    float ds = dsx * dsx + dsy * dsy;
    float dr = drx * drx + dry * dry;
    #pragma unroll
    for (int m = 1; m < 64; m <<= 1) { ds += __shfl_xor(ds, m); dr += __shfl_xor(dr, m); }
    const float sds = sqrtf(ds), sdr = sqrtf(dr);
    if (lane == 0) out_vals[i] = sds - sdr;
    const float is = 1.0f / sds, ir = 1.0f / sdr;
    float2 gr;
    gr.x = dsx * is - drx * ir;
    gr.y = dsy * is - dry * ir;
    *reinterpret_cast<float2*>(out_grads + (size_t)i * DIM + 2 * lane) = gr;
}

extern "C" void kernel_launch(void* const* d_in, const int* in_sizes, int n_in,
                              void* d_out, int out_size, void* d_ws, size_t ws_size,
                              hipStream_t stream) {
    const float* target  = (const float*)d_in[0];
    const float* reached = (const float*)d_in[1];
    const int n_total = in_sizes[0] / DIM;
    const int nprev = n_total - BATCH;

    const float* tg   = target  + (size_t)nprev * DIM;
    const float* rg   = reached + (size_t)nprev * DIM;
    const float* prev = reached;

    float* out_vals  = (float*)d_out;
    float* out_grads = out_vals + BATCH;

    const size_t offB  = 0;                                 // 16 MiB (1024 x 16KB imgs)
    const size_t offA  = (size_t)1024 * 8192 * 2;           // 512 KiB (16 x 32KB imgs)
    const size_t offP2 = offA + (size_t)16 * 16384 * 2;     // 256 KiB (p2h)
    const size_t offPP = offP2 + (size_t)NPREV * 4;         // 4 MiB  (p2 partials)
    const size_t offPt = offPP + (size_t)NPREV * 16 * 4;    // 1 MiB  (partial top-2)
    const size_t need  = offPt + (size_t)BATCH * NCH * sizeof(float4);

    if (nprev == NPREV && ws_size >= need) {
        u16*    Bb      = (u16*)((char*)d_ws + offB);
        u16*    Ab      = (u16*)((char*)d_ws + offA);
        float*  p2h     = (float*)((char*)d_ws + offP2);
        float*  p2part  = (float*)((char*)d_ws + offPP);
        float4* partial = (float4*)((char*)d_ws + offPt);

        k_convB<<<(1024 * 1024) / 256, 256, 0, stream>>>(prev, Bb, p2part);
        k_convA<<<(16 * 2048) / 256, 256, 0, stream>>>(tg, Ab);
        k_prev2r<<<NPREV / 256, 256, 0, stream>>>(p2part, p2h);
        k_gemm_argmin<<<256, 512, 0, stream>>>(Ab, Bb, p2h, partial);
        k_final2<<<BATCH / 4, 256, 0, stream>>>(tg, rg, prev, (const float2*)partial,
                                                out_vals, out_grads);
    } else {
        float*  prev2   = (float*)d_ws;
        float2* partial = (float2*)((char*)d_ws + (size_t)nprev * sizeof(float));
        k_prev2<<<nprev / 4, 256, 0, stream>>>(prev, prev2, nprev);
        dim3 grid(BATCH / TM, FNCHUNK);
        k_argmin_fb<<<grid, 256, 0, stream>>>(tg, prev, prev2, partial);
        k_final_fb<<<BATCH / 4, 256, 0, stream>>>(tg, rg, prev, partial, out_vals, out_grads);
    }
}